// Round 2
// baseline (8528.602 us; speedup 1.0000x reference)
//
#include <hip/hip_runtime.h>

#define BB 256
#define TT 256
#define NN 512
#define HH 512

typedef short short8 __attribute__((ext_vector_type(8)));
typedef float f32x4 __attribute__((ext_vector_type(4)));

static __device__ __forceinline__ ushort f2bf(float f) {
  uint b = __builtin_bit_cast(uint, f);
  b += 0x7FFFu + ((b >> 16) & 1u);
  return (ushort)(b >> 16);
}
static __device__ __forceinline__ uint pk2(float lo, float hi) {
  return (uint)f2bf(lo) | ((uint)f2bf(hi) << 16);
}
static __device__ __forceinline__ float sigmoidf_(float x) {
  return 1.0f / (1.0f + expf(-x));
}

// ---------------------------------------------------------------------------
// Prep: W2 = [w_ih | w_hh] bf16 (2048 x 1024), b_gate = b_ih + b_hh,
// hb0 = h0, zero the group barrier counters.
// ---------------------------------------------------------------------------
__global__ __launch_bounds__(256) void prep_kernel(
    const float* __restrict__ w_ih, const float* __restrict__ w_hh,
    const float* __restrict__ b_ih, const float* __restrict__ b_hh,
    const float* __restrict__ h0,
    ushort* __restrict__ W2, float* __restrict__ bgate,
    float* __restrict__ hb0, unsigned* __restrict__ bar) {
  int idx = blockIdx.x * 256 + threadIdx.x;
  if (idx < 2048 * 1024) {
    int row = idx >> 10;
    int k = idx & 1023;
    float v = (k < NN) ? w_ih[row * NN + k] : w_hh[row * HH + (k - NN)];
    W2[idx] = f2bf(v);
  }
  if (idx < 2048) bgate[idx] = b_ih[idx] + b_hh[idx];
  if (idx < BB * HH) hb0[idx] = h0[idx];
  if (idx < 16) bar[idx] = 0u;
}

// ---------------------------------------------------------------------------
// Attention: a = softmax_n(proj_x) is timestep-invariant (softmax shift
// invariance kills the h/c/bias terms). Write a to ws, broadcast to output.
// ---------------------------------------------------------------------------
__global__ __launch_bounds__(256) void attn_kernel(
    const float* __restrict__ x, const float* __restrict__ attn_w,
    float* __restrict__ a_out, float* __restrict__ attn_out) {
  __shared__ float wx[TT];
  __shared__ float red[8];
  const int b = blockIdx.x;
  const int tid = threadIdx.x;
  wx[tid] = attn_w[2 * HH + tid];
  __syncthreads();

  const float* xb = x + (size_t)b * TT * NN;
  float p0 = 0.0f, p1 = 0.0f;
  for (int t = 0; t < TT; ++t) {
    float w = wx[t];
    p0 += xb[t * NN + tid] * w;
    p1 += xb[t * NN + 256 + tid] * w;
  }

  const int lane = tid & 63, wv = tid >> 6;
  float m = fmaxf(p0, p1);
  #pragma unroll
  for (int o = 32; o; o >>= 1) m = fmaxf(m, __shfl_xor(m, o));
  if (lane == 0) red[wv] = m;
  __syncthreads();
  m = fmaxf(fmaxf(red[0], red[1]), fmaxf(red[2], red[3]));
  float e0 = expf(p0 - m), e1 = expf(p1 - m);
  float s = e0 + e1;
  #pragma unroll
  for (int o = 32; o; o >>= 1) s += __shfl_xor(s, o);
  if (lane == 0) red[4 + wv] = s;
  __syncthreads();
  s = red[4] + red[5] + red[6] + red[7];
  float inv = 1.0f / s;
  float a0 = e0 * inv, a1 = e1 * inv;
  a_out[b * NN + tid] = a0;
  a_out[b * NN + 256 + tid] = a1;

  float* ob = attn_out + (size_t)b * TT * NN;
  for (int t = 0; t < TT; ++t) {
    ob[t * NN + tid] = a0;
    ob[t * NN + 256 + tid] = a1;
  }
}

// ---------------------------------------------------------------------------
// Persistent LSTM: 256 blocks (16 bg x 16 jt), 512 threads (8 waves).
// W2 slice register-resident (32 short8 frags/lane). c register-resident.
// Per step: stage a*x_t -> x-half MFMAs -> wait h barrier -> stage h ->
// h-half MFMAs -> elementwise -> publish h -> arrive.
// Per-bg barrier: monotonic counter, device-scope release/acquire fences
// (correct under cross-XCD L2 non-coherence).
// ---------------------------------------------------------------------------
__global__ __launch_bounds__(512, 2) void lstm_persistent(
    const float* __restrict__ x,     // (B,T,N)
    const float* __restrict__ a,     // (B,N)
    const ushort* __restrict__ W2,   // (2048,1024) bf16
    const float* __restrict__ bgate, // (2048)
    const float* __restrict__ c0,    // (B,H)
    float* __restrict__ hb0, float* __restrict__ hb1,
    float* __restrict__ enc,         // (B,T,H)
    unsigned* __restrict__ bar) {
  __shared__ ushort Alds[16 * 1024];  // 32 KB, 16B-granule XOR swizzle
  __shared__ float ex[128][17];       // 8.7 KB gate exchange

  const int tid = threadIdx.x;
  const int lane = tid & 63;
  const int wid = tid >> 6;
  const int bg = blockIdx.x >> 4;
  const int jt = blockIdx.x & 15;
  const int gb0 = bg * 16;

  // ---- register-resident W2 fragments: wave owns block rows wid*16..+15
  short8 bfrag[32];
  {
    const int r = wid * 16 + (lane & 15);          // block row 0..127
    const int grow = (r >> 5) * 512 + jt * 32 + (r & 31);
    const ushort* wp = W2 + (size_t)grow * 1024 + ((lane >> 4) << 3);
    #pragma unroll
    for (int kc = 0; kc < 32; ++kc)
      bfrag[kc] = *(const short8*)(wp + kc * 32);
  }

  // ---- staging geometry: thread = (srow 0..15, sl 0..31)
  const int srow = tid >> 5;
  const int sl = tid & 31;
  const int r7 = srow & 7;
  // attention weights for this thread's fixed columns (registers, loaded once)
  float4 a0v, a1v, a2v, a3v;
  {
    const float* ap = a + (size_t)(gb0 + srow) * NN;
    a0v = *(const float4*)(ap + sl * 8);
    a1v = *(const float4*)(ap + sl * 8 + 4);
    a2v = *(const float4*)(ap + 256 + sl * 8);
    a3v = *(const float4*)(ap + 256 + sl * 8 + 4);
  }

  // ---- elementwise geometry: thread owns (batch eb, col ecol)
  const int eb = tid >> 5;
  const int ejj = tid & 31;
  const int ecol = jt * 32 + ejj;
  const float bgi = bgate[ecol];
  const float bgf = bgate[512 + ecol];
  const float bgg = bgate[1024 + ecol];
  const float bgo = bgate[1536 + ecol];
  float c_reg = c0[(size_t)(gb0 + eb) * HH + ecol];

  const int ar = lane & 15;
  const int kq = lane >> 4;
  const int abase = ar * 1024;
  const int ar7 = ar & 7;

  for (int t = 0; t < TT; ++t) {
    const float* hin = (t & 1) ? hb1 : hb0;
    float* hout = (t & 1) ? hb0 : hb1;

    // ---- stage x-part of A: cols [8sl,8sl+8) and [256+8sl, +8)
    {
      const float* xp = x + ((size_t)(gb0 + srow) * TT + t) * NN;
      const float4 x0 = *(const float4*)(xp + sl * 8);
      const float4 x1 = *(const float4*)(xp + sl * 8 + 4);
      const float4 x2 = *(const float4*)(xp + 256 + sl * 8);
      const float4 x3 = *(const float4*)(xp + 256 + sl * 8 + 4);
      uint4 p0, p1;
      p0.x = pk2(x0.x * a0v.x, x0.y * a0v.y);
      p0.y = pk2(x0.z * a0v.z, x0.w * a0v.w);
      p0.z = pk2(x1.x * a1v.x, x1.y * a1v.y);
      p0.w = pk2(x1.z * a1v.z, x1.w * a1v.w);
      p1.x = pk2(x2.x * a2v.x, x2.y * a2v.y);
      p1.y = pk2(x2.z * a2v.z, x2.w * a2v.w);
      p1.z = pk2(x3.x * a3v.x, x3.y * a3v.y);
      p1.w = pk2(x3.z * a3v.z, x3.w * a3v.w);
      *(uint4*)&Alds[srow * 1024 + ((sl ^ r7) << 3)] = p0;
      *(uint4*)&Alds[srow * 1024 + (((32 + sl) ^ r7) << 3)] = p1;
    }
    __syncthreads();  // B1

    // ---- x-half GEMM (no h dependency): bfrag[0..15]
    f32x4 accx = {0.f, 0.f, 0.f, 0.f};
    #pragma unroll
    for (int kc = 0; kc < 16; ++kc) {
      const int ag = kc * 4 + kq;
      short8 af = *(const short8*)&Alds[abase + ((ag ^ ar7) << 3)];
      accx = __builtin_amdgcn_mfma_f32_16x16x32_bf16(af, bfrag[kc], accx, 0, 0, 0);
    }

    // ---- wait for h_t (writes of step t-1 across the bg group)
    if (t) {
      if (tid == 0) {
        const unsigned target = 16u * (unsigned)t;
        while (__hip_atomic_load(bar + bg, __ATOMIC_ACQUIRE,
                                 __HIP_MEMORY_SCOPE_AGENT) < target)
          __builtin_amdgcn_s_sleep(8);
        __threadfence();  // acquire: invalidate stale L1/L2
      }
    }
    __syncthreads();  // B2

    // ---- stage h-part of A
    {
      const float* hp = hin + (size_t)(gb0 + srow) * HH;
      const float4 h0v = *(const float4*)(hp + sl * 8);
      const float4 h1v = *(const float4*)(hp + sl * 8 + 4);
      const float4 h2v = *(const float4*)(hp + 256 + sl * 8);
      const float4 h3v = *(const float4*)(hp + 256 + sl * 8 + 4);
      uint4 p0, p1;
      p0.x = pk2(h0v.x, h0v.y);
      p0.y = pk2(h0v.z, h0v.w);
      p0.z = pk2(h1v.x, h1v.y);
      p0.w = pk2(h1v.z, h1v.w);
      p1.x = pk2(h2v.x, h2v.y);
      p1.y = pk2(h2v.z, h2v.w);
      p1.z = pk2(h3v.x, h3v.y);
      p1.w = pk2(h3v.z, h3v.w);
      *(uint4*)&Alds[srow * 1024 + (((64 + sl) ^ r7) << 3)] = p0;
      *(uint4*)&Alds[srow * 1024 + (((96 + sl) ^ r7) << 3)] = p1;
    }
    __syncthreads();  // B3

    // ---- h-half GEMM: bfrag[16..31]
    f32x4 acch = {0.f, 0.f, 0.f, 0.f};
    #pragma unroll
    for (int kc = 16; kc < 32; ++kc) {
      const int ag = kc * 4 + kq;
      short8 af = *(const short8*)&Alds[abase + ((ag ^ ar7) << 3)];
      acch = __builtin_amdgcn_mfma_f32_16x16x32_bf16(af, bfrag[kc], acch, 0, 0, 0);
    }

    // ---- exchange gates: D layout col=lane&15 (gate-row), row=(lane>>4)*4+e
    {
      const f32x4 accf = accx + acch;
      const int c = lane & 15;
      const int rb = (lane >> 4) << 2;
      const int r = wid * 16 + c;
      #pragma unroll
      for (int e = 0; e < 4; ++e) ex[r][rb + e] = accf[e];
    }
    __syncthreads();  // B4

    // ---- elementwise LSTM cell (c stays in register)
    {
      float ig = ex[ejj][eb] + bgi;
      float fg = ex[32 + ejj][eb] + bgf;
      float gg = ex[64 + ejj][eb] + bgg;
      float og = ex[96 + ejj][eb] + bgo;
      ig = sigmoidf_(ig);
      fg = sigmoidf_(fg);
      gg = tanhf(gg);
      og = sigmoidf_(og);
      const float cn = fg * c_reg + ig * gg;
      const float hn = og * tanhf(cn);
      c_reg = cn;
      hout[(size_t)(gb0 + eb) * HH + ecol] = hn;
      enc[((size_t)(gb0 + eb) * TT + t) * HH + ecol] = hn;
    }
    __syncthreads();  // B5: barrier drains vmcnt -> stores complete to L2

    // ---- publish h: device-scope release + arrive
    if (tid == 0) {
      __threadfence();  // writeback L2 (cross-XCD visibility)
      __hip_atomic_fetch_add(bar + bg, 1u, __ATOMIC_RELEASE,
                             __HIP_MEMORY_SCOPE_AGENT);
    }
  }
}

extern "C" void kernel_launch(void* const* d_in, const int* in_sizes, int n_in,
                              void* d_out, int out_size, void* d_ws, size_t ws_size,
                              hipStream_t stream) {
  const float* x      = (const float*)d_in[0];
  const float* h0     = (const float*)d_in[1];
  const float* c0     = (const float*)d_in[2];
  const float* attn_w = (const float*)d_in[3];
  // d_in[4] = attn_b: softmax-shift-invariant -> unused
  const float* w_ih   = (const float*)d_in[5];
  const float* w_hh   = (const float*)d_in[6];
  const float* b_ih   = (const float*)d_in[7];
  const float* b_hh   = (const float*)d_in[8];

  float* attn_out = (float*)d_out;                         // (B,T,N)
  float* enc_out  = (float*)d_out + (size_t)BB * TT * NN;  // (B,T,H)

  char* ws = (char*)d_ws;
  float*    a_ws  = (float*)(ws);                    // 512 KB
  ushort*   W2_ws = (ushort*)(ws + 0x80000);         // 4 MB
  float*    bg_ws = (float*)(ws + 0x480000);         // 8 KB
  float*    hb0   = (float*)(ws + 0x482000);         // 512 KB
  float*    hb1   = (float*)(ws + 0x502000);         // 512 KB
  unsigned* bar   = (unsigned*)(ws + 0x582000);      // 64 B

  prep_kernel<<<8192, 256, 0, stream>>>(w_ih, w_hh, b_ih, b_hh, h0,
                                        W2_ws, bg_ws, hb0, bar);
  attn_kernel<<<BB, 256, 0, stream>>>(x, attn_w, a_ws, attn_out);

  dim3 grid(256), block(512);
  void* args[] = {(void*)&x, (void*)&a_ws, (void*)&W2_ws, (void*)&bg_ws,
                  (void*)&c0, (void*)&hb0, (void*)&hb1, (void*)&enc_out,
                  (void*)&bar};
  hipLaunchCooperativeKernel((void*)lstm_persistent, grid, block, args, 0, stream);
}

// Round 3
// 3753.746 us; speedup vs baseline: 2.2720x; 2.2720x over previous
//
#include <hip/hip_runtime.h>

#define BB 256
#define TT 256
#define NN 512
#define HH 512

typedef short short8 __attribute__((ext_vector_type(8)));
typedef float f32x4 __attribute__((ext_vector_type(4)));

static __device__ __forceinline__ ushort f2bf(float f) {
  uint b = __builtin_bit_cast(uint, f);
  b += 0x7FFFu + ((b >> 16) & 1u);
  return (ushort)(b >> 16);
}
static __device__ __forceinline__ uint pk2(float lo, float hi) {
  return (uint)f2bf(lo) | ((uint)f2bf(hi) << 16);
}
static __device__ __forceinline__ uint pkq(unsigned long long q) {
  float lo = __builtin_bit_cast(float, (uint)q);
  float hi = __builtin_bit_cast(float, (uint)(q >> 32));
  return pk2(lo, hi);
}
static __device__ __forceinline__ float sigmoidf_(float x) {
  return 1.0f / (1.0f + expf(-x));
}

// ---------------------------------------------------------------------------
// Prep: W2 = [w_ih | w_hh] bf16 (2048 x 1024), b_gate = b_ih + b_hh,
// hb0 = h0, zero the group barrier counters (every launch - deterministic).
// ---------------------------------------------------------------------------
__global__ __launch_bounds__(256) void prep_kernel(
    const float* __restrict__ w_ih, const float* __restrict__ w_hh,
    const float* __restrict__ b_ih, const float* __restrict__ b_hh,
    const float* __restrict__ h0,
    ushort* __restrict__ W2, float* __restrict__ bgate,
    float* __restrict__ hb0, unsigned* __restrict__ bar) {
  int idx = blockIdx.x * 256 + threadIdx.x;
  if (idx < 2048 * 1024) {
    int row = idx >> 10;
    int k = idx & 1023;
    float v = (k < NN) ? w_ih[row * NN + k] : w_hh[row * HH + (k - NN)];
    W2[idx] = f2bf(v);
  }
  if (idx < 2048) bgate[idx] = b_ih[idx] + b_hh[idx];
  if (idx < BB * HH) hb0[idx] = h0[idx];
  if (idx < 16) bar[idx] = 0u;
}

// ---------------------------------------------------------------------------
// Attention: a = softmax_n(proj_x) is timestep-invariant (softmax shift
// invariance kills the h/c/bias terms). Write a to ws, broadcast to output.
// ---------------------------------------------------------------------------
__global__ __launch_bounds__(256) void attn_kernel(
    const float* __restrict__ x, const float* __restrict__ attn_w,
    float* __restrict__ a_out, float* __restrict__ attn_out) {
  __shared__ float wx[TT];
  __shared__ float red[8];
  const int b = blockIdx.x;
  const int tid = threadIdx.x;
  wx[tid] = attn_w[2 * HH + tid];
  __syncthreads();

  const float* xb = x + (size_t)b * TT * NN;
  float p0 = 0.0f, p1 = 0.0f;
  for (int t = 0; t < TT; ++t) {
    float w = wx[t];
    p0 += xb[t * NN + tid] * w;
    p1 += xb[t * NN + 256 + tid] * w;
  }

  const int lane = tid & 63, wv = tid >> 6;
  float m = fmaxf(p0, p1);
  #pragma unroll
  for (int o = 32; o; o >>= 1) m = fmaxf(m, __shfl_xor(m, o));
  if (lane == 0) red[wv] = m;
  __syncthreads();
  m = fmaxf(fmaxf(red[0], red[1]), fmaxf(red[2], red[3]));
  float e0 = expf(p0 - m), e1 = expf(p1 - m);
  float s = e0 + e1;
  #pragma unroll
  for (int o = 32; o; o >>= 1) s += __shfl_xor(s, o);
  if (lane == 0) red[4 + wv] = s;
  __syncthreads();
  s = red[4] + red[5] + red[6] + red[7];
  float inv = 1.0f / s;
  float a0 = e0 * inv, a1 = e1 * inv;
  a_out[b * NN + tid] = a0;
  a_out[b * NN + 256 + tid] = a1;

  float* ob = attn_out + (size_t)b * TT * NN;
  for (int t = 0; t < TT; ++t) {
    ob[t * NN + tid] = a0;
    ob[t * NN + 256 + tid] = a1;
  }
}

// ---------------------------------------------------------------------------
// Persistent LSTM: 256 blocks (16 bg x 16 jt), 512 threads (8 waves).
// W2 slice register-resident. c register-resident. Cross-block h exchange and
// barrier use RELAXED AGENT-scope atomics (sc1, coherent at Infinity Cache) --
// NO fences, NO buffer_inv/buffer_wbl2 L2 flushes (the round-2 8.5ms lesson).
// Ordering: h stores are vmcnt-drained before the signal add (compiler drains
// at the pre-arrive s_barrier; explicit vmcnt(0) on the signaling lane); the
// consumer's h loads are atomic (non-speculatable) issued only after the poll
// succeeds, reading the same coherence point.
// ---------------------------------------------------------------------------
__global__ __launch_bounds__(512, 2) void lstm_persistent(
    const float* __restrict__ x,     // (B,T,N)
    const float* __restrict__ a,     // (B,N)
    const ushort* __restrict__ W2,   // (2048,1024) bf16
    const float* __restrict__ bgate, // (2048)
    const float* __restrict__ c0,    // (B,H)
    float* __restrict__ hb0, float* __restrict__ hb1,
    float* __restrict__ enc,         // (B,T,H)
    unsigned* __restrict__ bar) {
  __shared__ ushort Alds[16 * 1024];  // 32 KB, 16B-granule XOR swizzle
  __shared__ float ex[128][17];       // 8.7 KB gate exchange

  const int tid = threadIdx.x;
  const int lane = tid & 63;
  const int wid = tid >> 6;
  const int bg = blockIdx.x >> 4;
  const int jt = blockIdx.x & 15;
  const int gb0 = bg * 16;

  // ---- register-resident W2 fragments: wave owns block rows wid*16..+15
  short8 bfrag[32];
  {
    const int r = wid * 16 + (lane & 15);          // block row 0..127
    const int grow = (r >> 5) * 512 + jt * 32 + (r & 31);
    const ushort* wp = W2 + (size_t)grow * 1024 + ((lane >> 4) << 3);
    #pragma unroll
    for (int kc = 0; kc < 32; ++kc)
      bfrag[kc] = *(const short8*)(wp + kc * 32);
  }

  // ---- staging geometry: thread = (srow 0..15, sl 0..31)
  const int srow = tid >> 5;
  const int sl = tid & 31;
  const int r7 = srow & 7;
  float4 a0v, a1v, a2v, a3v;
  {
    const float* ap = a + (size_t)(gb0 + srow) * NN;
    a0v = *(const float4*)(ap + sl * 8);
    a1v = *(const float4*)(ap + sl * 8 + 4);
    a2v = *(const float4*)(ap + 256 + sl * 8);
    a3v = *(const float4*)(ap + 256 + sl * 8 + 4);
  }

  // ---- elementwise geometry: thread owns (batch eb, col ecol)
  const int eb = tid >> 5;
  const int ejj = tid & 31;
  const int ecol = jt * 32 + ejj;
  const float bgi = bgate[ecol];
  const float bgf = bgate[512 + ecol];
  const float bgg = bgate[1024 + ecol];
  const float bgo = bgate[1536 + ecol];
  float c_reg = c0[(size_t)(gb0 + eb) * HH + ecol];

  const int ar = lane & 15;
  const int kq = lane >> 4;
  const int abase = ar * 1024;
  const int ar7 = ar & 7;

  for (int t = 0; t < TT; ++t) {
    const float* hin = (t & 1) ? hb1 : hb0;
    float* hout = (t & 1) ? hb0 : hb1;

    // ---- stage x-part of A: cols [8sl,8sl+8) and [256+8sl, +8)
    {
      const float* xp = x + ((size_t)(gb0 + srow) * TT + t) * NN;
      const float4 x0 = *(const float4*)(xp + sl * 8);
      const float4 x1 = *(const float4*)(xp + sl * 8 + 4);
      const float4 x2 = *(const float4*)(xp + 256 + sl * 8);
      const float4 x3 = *(const float4*)(xp + 256 + sl * 8 + 4);
      uint4 p0, p1;
      p0.x = pk2(x0.x * a0v.x, x0.y * a0v.y);
      p0.y = pk2(x0.z * a0v.z, x0.w * a0v.w);
      p0.z = pk2(x1.x * a1v.x, x1.y * a1v.y);
      p0.w = pk2(x1.z * a1v.z, x1.w * a1v.w);
      p1.x = pk2(x2.x * a2v.x, x2.y * a2v.y);
      p1.y = pk2(x2.z * a2v.z, x2.w * a2v.w);
      p1.z = pk2(x3.x * a3v.x, x3.y * a3v.y);
      p1.w = pk2(x3.z * a3v.z, x3.w * a3v.w);
      *(uint4*)&Alds[srow * 1024 + ((sl ^ r7) << 3)] = p0;
      *(uint4*)&Alds[srow * 1024 + (((32 + sl) ^ r7) << 3)] = p1;
    }
    __syncthreads();  // B1

    // ---- x-half GEMM (no h dependency): bfrag[0..15]
    f32x4 accx = {0.f, 0.f, 0.f, 0.f};
    #pragma unroll
    for (int kc = 0; kc < 16; ++kc) {
      const int ag = kc * 4 + kq;
      short8 af = *(const short8*)&Alds[abase + ((ag ^ ar7) << 3)];
      accx = __builtin_amdgcn_mfma_f32_16x16x32_bf16(af, bfrag[kc], accx, 0, 0, 0);
    }

    // ---- wait for h_t (all 16 blocks of this bg arrived at end of t-1)
    if (t) {
      if (tid == 0) {
        const unsigned target = 16u * (unsigned)t;
        while (__hip_atomic_load(bar + bg, __ATOMIC_RELAXED,
                                 __HIP_MEMORY_SCOPE_AGENT) < target)
          __builtin_amdgcn_s_sleep(1);
      }
    }
    __syncthreads();  // B2

    // ---- stage h-part of A (agent-scope coherent loads, no fence)
    {
      const float* hp = hin + (size_t)(gb0 + srow) * HH;
      unsigned long long q[8];
      #pragma unroll
      for (int j = 0; j < 4; ++j)
        q[j] = __hip_atomic_load(
            (const unsigned long long*)(hp + sl * 8 + j * 2),
            __ATOMIC_RELAXED, __HIP_MEMORY_SCOPE_AGENT);
      #pragma unroll
      for (int j = 0; j < 4; ++j)
        q[4 + j] = __hip_atomic_load(
            (const unsigned long long*)(hp + 256 + sl * 8 + j * 2),
            __ATOMIC_RELAXED, __HIP_MEMORY_SCOPE_AGENT);
      uint4 p0, p1;
      p0.x = pkq(q[0]); p0.y = pkq(q[1]); p0.z = pkq(q[2]); p0.w = pkq(q[3]);
      p1.x = pkq(q[4]); p1.y = pkq(q[5]); p1.z = pkq(q[6]); p1.w = pkq(q[7]);
      *(uint4*)&Alds[srow * 1024 + (((64 + sl) ^ r7) << 3)] = p0;
      *(uint4*)&Alds[srow * 1024 + (((96 + sl) ^ r7) << 3)] = p1;
    }
    __syncthreads();  // B3

    // ---- h-half GEMM: bfrag[16..31]
    f32x4 acch = {0.f, 0.f, 0.f, 0.f};
    #pragma unroll
    for (int kc = 16; kc < 32; ++kc) {
      const int ag = kc * 4 + kq;
      short8 af = *(const short8*)&Alds[abase + ((ag ^ ar7) << 3)];
      acch = __builtin_amdgcn_mfma_f32_16x16x32_bf16(af, bfrag[kc], acch, 0, 0, 0);
    }

    // ---- exchange gates: D layout col=lane&15 (gate-row), row=(lane>>4)*4+e
    {
      const f32x4 accf = accx + acch;
      const int c = lane & 15;
      const int rb = (lane >> 4) << 2;
      const int r = wid * 16 + c;
      #pragma unroll
      for (int e = 0; e < 4; ++e) ex[r][rb + e] = accf[e];
    }
    __syncthreads();  // B4

    // ---- elementwise LSTM cell (c stays in register)
    {
      float ig = ex[ejj][eb] + bgi;
      float fg = ex[32 + ejj][eb] + bgf;
      float gg = ex[64 + ejj][eb] + bgg;
      float og = ex[96 + ejj][eb] + bgo;
      ig = sigmoidf_(ig);
      fg = sigmoidf_(fg);
      gg = tanhf(gg);
      og = sigmoidf_(og);
      const float cn = fg * c_reg + ig * gg;
      const float hn = og * tanhf(cn);
      c_reg = cn;
      // h publish: agent-scope coherent store (write-through to MALL)
      __hip_atomic_store((uint*)&hout[(size_t)(gb0 + eb) * HH + ecol],
                         __builtin_bit_cast(uint, hn),
                         __ATOMIC_RELAXED, __HIP_MEMORY_SCOPE_AGENT);
      enc[((size_t)(gb0 + eb) * TT + t) * HH + ecol] = hn;
    }
    __syncthreads();  // B5: every thread's stores vmcnt-drained before arrive

    // ---- signal: all h stores of this block are at the coherence point
    if (tid == 0) {
      asm volatile("s_waitcnt vmcnt(0)" ::: "memory");
      __hip_atomic_fetch_add(bar + bg, 1u, __ATOMIC_RELAXED,
                             __HIP_MEMORY_SCOPE_AGENT);
    }
  }
}

extern "C" void kernel_launch(void* const* d_in, const int* in_sizes, int n_in,
                              void* d_out, int out_size, void* d_ws, size_t ws_size,
                              hipStream_t stream) {
  const float* x      = (const float*)d_in[0];
  const float* h0     = (const float*)d_in[1];
  const float* c0     = (const float*)d_in[2];
  const float* attn_w = (const float*)d_in[3];
  // d_in[4] = attn_b: softmax-shift-invariant -> unused
  const float* w_ih   = (const float*)d_in[5];
  const float* w_hh   = (const float*)d_in[6];
  const float* b_ih   = (const float*)d_in[7];
  const float* b_hh   = (const float*)d_in[8];

  float* attn_out = (float*)d_out;                         // (B,T,N)
  float* enc_out  = (float*)d_out + (size_t)BB * TT * NN;  // (B,T,H)

  char* ws = (char*)d_ws;
  float*    a_ws  = (float*)(ws);                    // 512 KB
  ushort*   W2_ws = (ushort*)(ws + 0x80000);         // 4 MB
  float*    bg_ws = (float*)(ws + 0x480000);         // 8 KB
  float*    hb0   = (float*)(ws + 0x482000);         // 512 KB
  float*    hb1   = (float*)(ws + 0x502000);         // 512 KB
  unsigned* bar   = (unsigned*)(ws + 0x582000);      // 64 B

  prep_kernel<<<8192, 256, 0, stream>>>(w_ih, w_hh, b_ih, b_hh, h0,
                                        W2_ws, bg_ws, hb0, bar);
  attn_kernel<<<BB, 256, 0, stream>>>(x, attn_w, a_ws, attn_out);

  dim3 grid(256), block(512);
  void* args[] = {(void*)&x, (void*)&a_ws, (void*)&W2_ws, (void*)&bg_ws,
                  (void*)&c0, (void*)&hb0, (void*)&hb1, (void*)&enc_out,
                  (void*)&bar};
  hipLaunchCooperativeKernel((void*)lstm_persistent, grid, block, args, 0, stream);
}

// Round 4
// 2159.430 us; speedup vs baseline: 3.9495x; 1.7383x over previous
//
#include <hip/hip_runtime.h>

#define BB 256
#define TT 256
#define NN 512
#define HH 512

typedef short short8 __attribute__((ext_vector_type(8)));
typedef float f32x4 __attribute__((ext_vector_type(4)));

static __device__ __forceinline__ ushort f2bf(float f) {
  uint b = __builtin_bit_cast(uint, f);
  b += 0x7FFFu + ((b >> 16) & 1u);
  return (ushort)(b >> 16);
}
static __device__ __forceinline__ uint pk2(float lo, float hi) {
  return (uint)f2bf(lo) | ((uint)f2bf(hi) << 16);
}
static __device__ __forceinline__ uint pkq(unsigned long long q) {
  float lo = __builtin_bit_cast(float, (uint)q);
  float hi = __builtin_bit_cast(float, (uint)(q >> 32));
  return pk2(lo, hi);
}
static __device__ __forceinline__ float sigmoidf_(float x) {
  return 1.0f / (1.0f + expf(-x));
}

// ---------------------------------------------------------------------------
// Prep: W2 = [w_ih | w_hh] bf16 (2048 x 1024), b_gate = b_ih + b_hh,
// hb0 = h0 (f32), zero barrier counters.
// ---------------------------------------------------------------------------
__global__ __launch_bounds__(256) void prep_kernel(
    const float* __restrict__ w_ih, const float* __restrict__ w_hh,
    const float* __restrict__ b_ih, const float* __restrict__ b_hh,
    const float* __restrict__ h0,
    ushort* __restrict__ W2, float* __restrict__ bgate,
    float* __restrict__ hb0, unsigned* __restrict__ bar) {
  int idx = blockIdx.x * 256 + threadIdx.x;
  if (idx < 2048 * 1024) {
    int row = idx >> 10;
    int k = idx & 1023;
    float v = (k < NN) ? w_ih[row * NN + k] : w_hh[row * HH + (k - NN)];
    W2[idx] = f2bf(v);
  }
  if (idx < 2048) bgate[idx] = b_ih[idx] + b_hh[idx];
  if (idx < BB * HH) hb0[idx] = h0[idx];
  if (idx < 16) bar[idx] = 0u;
}

// ---------------------------------------------------------------------------
// Attention: a = softmax_n(proj_x) is timestep-invariant (softmax shift
// invariance kills the h/c/bias terms). Write a to ws, broadcast to output.
// ---------------------------------------------------------------------------
__global__ __launch_bounds__(256) void attn_kernel(
    const float* __restrict__ x, const float* __restrict__ attn_w,
    float* __restrict__ a_out, float* __restrict__ attn_out) {
  __shared__ float wx[TT];
  __shared__ float red[8];
  const int b = blockIdx.x;
  const int tid = threadIdx.x;
  wx[tid] = attn_w[2 * HH + tid];
  __syncthreads();

  const float* xb = x + (size_t)b * TT * NN;
  float p0 = 0.0f, p1 = 0.0f;
  for (int t = 0; t < TT; ++t) {
    float w = wx[t];
    p0 += xb[t * NN + tid] * w;
    p1 += xb[t * NN + 256 + tid] * w;
  }

  const int lane = tid & 63, wv = tid >> 6;
  float m = fmaxf(p0, p1);
  #pragma unroll
  for (int o = 32; o; o >>= 1) m = fmaxf(m, __shfl_xor(m, o));
  if (lane == 0) red[wv] = m;
  __syncthreads();
  m = fmaxf(fmaxf(red[0], red[1]), fmaxf(red[2], red[3]));
  float e0 = expf(p0 - m), e1 = expf(p1 - m);
  float s = e0 + e1;
  #pragma unroll
  for (int o = 32; o; o >>= 1) s += __shfl_xor(s, o);
  if (lane == 0) red[4 + wv] = s;
  __syncthreads();
  s = red[4] + red[5] + red[6] + red[7];
  float inv = 1.0f / s;
  float a0 = e0 * inv, a1 = e1 * inv;
  a_out[b * NN + tid] = a0;
  a_out[b * NN + 256 + tid] = a1;

  float* ob = attn_out + (size_t)b * TT * NN;
  for (int t = 0; t < TT; ++t) {
    ob[t * NN + tid] = a0;
    ob[t * NN + 256 + tid] = a1;
  }
}

// ---------------------------------------------------------------------------
// Persistent LSTM v4. 256 blocks, 512 threads (8 waves).
//   bg = blockIdx.x & 15  -> all 16 blocks of a bg group land on ONE XCD
//   jt = blockIdx.x >> 4     (i%8 round-robin heuristic): x-tile fetched once
//                            per group; h exchange stays near one L2.
// Operand swap: A = W2 rows (register-resident afrag, 16 rows/wave mapped
// r -> gate=r&3, col=r>>2), B = [a*x_t | h] panel from LDS. D layout then
// gives each lane all 4 gates of one (batch,col) -> elementwise fully
// in-lane: no gate-exchange LDS, no extra barriers. 2 barriers/step.
// Cross-block h + barrier via RELAXED agent atomics only (no fences).
// ---------------------------------------------------------------------------
__global__ __launch_bounds__(512, 2) void lstm_persistent(
    const float* __restrict__ x,     // (B,T,N)
    const float* __restrict__ a,     // (B,N)
    const ushort* __restrict__ W2,   // (2048,1024) bf16
    const float* __restrict__ bgate, // (2048)
    const float* __restrict__ c0,    // (B,H)
    float* __restrict__ hb0, float* __restrict__ hb1,
    float* __restrict__ enc,         // (B,T,H)
    unsigned* __restrict__ bar) {
  __shared__ ushort hx[16 * 1024];  // 32 KB panel [16 batch][1024 k], swizzled

  const int tid = threadIdx.x;
  const int lane = tid & 63;
  const int w = tid >> 6;           // wave 0..7
  const int bg = blockIdx.x & 15;   // XCD-local group
  const int jt = blockIdx.x >> 4;   // col tile 0..15
  const int gb0 = bg * 16;

  // ---- register-resident W2 A-fragments: wave's 16 rows, r->(gate,col)
  short8 afrag[32];
  {
    const int r = lane & 15;
    const int grow = (r & 3) * 512 + jt * 32 + w * 4 + (r >> 2);
    const ushort* wp = W2 + (size_t)grow * 1024 + ((lane >> 4) << 3);
    #pragma unroll
    for (int ks = 0; ks < 32; ++ks)
      afrag[ks] = *(const short8*)(wp + ks * 32);
  }

  // ---- staging geometry: thread = (srow 0..15, sl 0..31)
  const int srow = tid >> 5;
  const int sl = tid & 31;
  const int r7 = srow & 7;
  float4 a0v, a1v, a2v, a3v;
  {
    const float* ap = a + (size_t)(gb0 + srow) * NN;
    a0v = *(const float4*)(ap + sl * 8);
    a1v = *(const float4*)(ap + sl * 8 + 4);
    a2v = *(const float4*)(ap + 256 + sl * 8);
    a3v = *(const float4*)(ap + 256 + sl * 8 + 4);
  }

  // ---- per-lane output geometry: (batch eb, col ecol), 4 gates in acc[0..3]
  const int eb = lane & 15;
  const int kq = lane >> 4;
  const int ecol = jt * 32 + w * 4 + kq;
  const float bgi = bgate[ecol];
  const float bgf = bgate[512 + ecol];
  const float bgg = bgate[1024 + ecol];
  const float bgo = bgate[1536 + ecol];
  float c_reg = c0[(size_t)(gb0 + eb) * HH + ecol];

  // ---- MFMA B-read geometry (same swizzle as staging)
  const int bbase = (lane & 15) * 1024;
  const int br7 = (lane & 15) & 7;

  for (int t = 0; t < TT; ++t) {
    const float* hin = (t & 1) ? hb1 : hb0;
    float* hout = (t & 1) ? hb0 : hb1;

    // ---- stage x-part (no h dependency; loads issue before the poll)
    {
      const float* xp = x + ((size_t)(gb0 + srow) * TT + t) * NN;
      const float4 x0 = *(const float4*)(xp + sl * 8);
      const float4 x1 = *(const float4*)(xp + sl * 8 + 4);
      const float4 x2 = *(const float4*)(xp + 256 + sl * 8);
      const float4 x3 = *(const float4*)(xp + 256 + sl * 8 + 4);
      uint4 p0, p1;
      p0.x = pk2(x0.x * a0v.x, x0.y * a0v.y);
      p0.y = pk2(x0.z * a0v.z, x0.w * a0v.w);
      p0.z = pk2(x1.x * a1v.x, x1.y * a1v.y);
      p0.w = pk2(x1.z * a1v.z, x1.w * a1v.w);
      p1.x = pk2(x2.x * a2v.x, x2.y * a2v.y);
      p1.y = pk2(x2.z * a2v.z, x2.w * a2v.w);
      p1.z = pk2(x3.x * a3v.x, x3.y * a3v.y);
      p1.w = pk2(x3.z * a3v.z, x3.w * a3v.w);
      *(uint4*)&hx[srow * 1024 + ((sl ^ r7) << 3)] = p0;
      *(uint4*)&hx[srow * 1024 + (((32 + sl) ^ r7) << 3)] = p1;
    }

    // ---- per-wave poll: lane 0 spins (exec-masked), wave proceeds together
    if (t) {
      if (lane == 0) {
        const unsigned target = 16u * (unsigned)t;
        while (__hip_atomic_load(bar + bg, __ATOMIC_RELAXED,
                                 __HIP_MEMORY_SCOPE_AGENT) < target)
          __builtin_amdgcn_s_sleep(1);
      }
      asm volatile("" ::: "memory");  // keep h loads below the poll
    }

    // ---- stage h-part (agent-scope coherent loads, no fence)
    {
      const float* hp = hin + (size_t)(gb0 + srow) * HH;
      unsigned long long q[8];
      #pragma unroll
      for (int j = 0; j < 4; ++j)
        q[j] = __hip_atomic_load(
            (const unsigned long long*)(hp + sl * 8 + j * 2),
            __ATOMIC_RELAXED, __HIP_MEMORY_SCOPE_AGENT);
      #pragma unroll
      for (int j = 0; j < 4; ++j)
        q[4 + j] = __hip_atomic_load(
            (const unsigned long long*)(hp + 256 + sl * 8 + j * 2),
            __ATOMIC_RELAXED, __HIP_MEMORY_SCOPE_AGENT);
      uint4 p0, p1;
      p0.x = pkq(q[0]); p0.y = pkq(q[1]); p0.z = pkq(q[2]); p0.w = pkq(q[3]);
      p1.x = pkq(q[4]); p1.y = pkq(q[5]); p1.z = pkq(q[6]); p1.w = pkq(q[7]);
      *(uint4*)&hx[srow * 1024 + (((64 + sl) ^ r7) << 3)] = p0;
      *(uint4*)&hx[srow * 1024 + (((96 + sl) ^ r7) << 3)] = p1;
    }
    __syncthreads();  // B1: panel ready

    // ---- full K=1024 GEMM: D[row=W2row][col=batch]
    f32x4 acc = {0.f, 0.f, 0.f, 0.f};
    #pragma unroll
    for (int ks = 0; ks < 32; ++ks) {
      const int ag = ks * 4 + kq;
      short8 bf = *(const short8*)&hx[bbase + ((ag ^ br7) << 3)];
      acc = __builtin_amdgcn_mfma_f32_16x16x32_bf16(afrag[ks], bf, acc, 0, 0, 0);
    }

    // ---- in-lane LSTM cell: acc[e] = gate e for (eb, ecol)
    {
      const float ig = sigmoidf_(acc[0] + bgi);
      const float fg = sigmoidf_(acc[1] + bgf);
      const float gg = tanhf(acc[2] + bgg);
      const float og = sigmoidf_(acc[3] + bgo);
      const float cn = fg * c_reg + ig * gg;
      const float hn = og * tanhf(cn);
      c_reg = cn;
      __hip_atomic_store((uint*)&hout[(size_t)(gb0 + eb) * HH + ecol],
                         __builtin_bit_cast(uint, hn),
                         __ATOMIC_RELAXED, __HIP_MEMORY_SCOPE_AGENT);
      enc[((size_t)(gb0 + eb) * TT + t) * HH + ecol] = hn;
    }
    __syncthreads();  // B2: all waves' stores vmcnt-drained; LDS reads done

    // ---- signal
    if (tid == 0) {
      asm volatile("s_waitcnt vmcnt(0)" ::: "memory");
      __hip_atomic_fetch_add(bar + bg, 1u, __ATOMIC_RELAXED,
                             __HIP_MEMORY_SCOPE_AGENT);
    }
  }
}

extern "C" void kernel_launch(void* const* d_in, const int* in_sizes, int n_in,
                              void* d_out, int out_size, void* d_ws, size_t ws_size,
                              hipStream_t stream) {
  const float* x      = (const float*)d_in[0];
  const float* h0     = (const float*)d_in[1];
  const float* c0     = (const float*)d_in[2];
  const float* attn_w = (const float*)d_in[3];
  // d_in[4] = attn_b: softmax-shift-invariant -> unused
  const float* w_ih   = (const float*)d_in[5];
  const float* w_hh   = (const float*)d_in[6];
  const float* b_ih   = (const float*)d_in[7];
  const float* b_hh   = (const float*)d_in[8];

  float* attn_out = (float*)d_out;                         // (B,T,N)
  float* enc_out  = (float*)d_out + (size_t)BB * TT * NN;  // (B,T,H)

  char* ws = (char*)d_ws;
  float*    a_ws  = (float*)(ws);                    // 512 KB
  ushort*   W2_ws = (ushort*)(ws + 0x80000);         // 4 MB
  float*    bg_ws = (float*)(ws + 0x480000);         // 8 KB
  float*    hb0   = (float*)(ws + 0x482000);         // 512 KB
  float*    hb1   = (float*)(ws + 0x502000);         // 512 KB
  unsigned* bar   = (unsigned*)(ws + 0x582000);      // 64 B

  prep_kernel<<<8192, 256, 0, stream>>>(w_ih, w_hh, b_ih, b_hh, h0,
                                        W2_ws, bg_ws, hb0, bar);
  attn_kernel<<<BB, 256, 0, stream>>>(x, attn_w, a_ws, attn_out);

  dim3 grid(256), block(512);
  void* args[] = {(void*)&x, (void*)&a_ws, (void*)&W2_ws, (void*)&bg_ws,
                  (void*)&c0, (void*)&hb0, (void*)&hb1, (void*)&enc_out,
                  (void*)&bar};
  hipLaunchCooperativeKernel((void*)lstm_persistent, grid, block, args, 0, stream);
}

// Round 5
// 1146.042 us; speedup vs baseline: 7.4418x; 1.8843x over previous
//
#include <hip/hip_runtime.h>

#define BB 256
#define TT 256
#define NN 512
#define HH 512

typedef short short8 __attribute__((ext_vector_type(8)));
typedef float f32x4 __attribute__((ext_vector_type(4)));
typedef unsigned long long u64;

static __device__ __forceinline__ ushort f2bf(float f) {
  uint b = __builtin_bit_cast(uint, f);
  b += 0x7FFFu + ((b >> 16) & 1u);
  return (ushort)(b >> 16);
}
static __device__ __forceinline__ uint pk2(float lo, float hi) {
  return (uint)f2bf(lo) | ((uint)f2bf(hi) << 16);
}
static __device__ __forceinline__ float sigmoidf_(float x) {
  return 1.0f / (1.0f + expf(-x));
}

// ---------------------------------------------------------------------------
// Prep: W2 = [w_ih | w_hh] bf16 (2048 x 1024), b_gate = b_ih + b_hh,
// h0 packed bf16x2 -> hx16a, zero padded barrier counters (every launch).
// ---------------------------------------------------------------------------
__global__ __launch_bounds__(256) void prep_kernel(
    const float* __restrict__ w_ih, const float* __restrict__ w_hh,
    const float* __restrict__ b_ih, const float* __restrict__ b_hh,
    const float* __restrict__ h0,
    ushort* __restrict__ W2, float* __restrict__ bgate,
    uint* __restrict__ hx16a, unsigned* __restrict__ bar) {
  int idx = blockIdx.x * 256 + threadIdx.x;
  if (idx < 2048 * 1024) {
    int row = idx >> 10;
    int k = idx & 1023;
    float v = (k < NN) ? w_ih[row * NN + k] : w_hh[row * HH + (k - NN)];
    W2[idx] = f2bf(v);
  }
  if (idx < 2048) bgate[idx] = b_ih[idx] + b_hh[idx];
  if (idx < BB * HH / 2) hx16a[idx] = pk2(h0[2 * idx], h0[2 * idx + 1]);
  if (idx < 16 * 64) bar[idx] = 0u;
}

// ---------------------------------------------------------------------------
// Attention + ax precompute. a = softmax_n(proj_x) is timestep-invariant
// (softmax shift invariance kills the h/c/bias terms). Pass 1: proj+softmax
// -> a_ws. Pass 2: ax[b,t,n] = bf16(a[b,n] * x[b,t,n]) into the (temporarily
// borrowed) attentions output region -- the step kernel then stages A-panels
// with ZERO conversion VALU. attn_out itself is written by a final kernel.
// ---------------------------------------------------------------------------
__global__ __launch_bounds__(256) void attn_kernel(
    const float* __restrict__ x, const float* __restrict__ attn_w,
    float* __restrict__ a_out, ushort* __restrict__ ax) {
  __shared__ float wx[TT];
  __shared__ float as[NN];
  __shared__ float red[8];
  const int b = blockIdx.x;
  const int tid = threadIdx.x;
  wx[tid] = attn_w[2 * HH + tid];
  __syncthreads();

  const float* xb = x + (size_t)b * TT * NN;
  float p0 = 0.0f, p1 = 0.0f;
  for (int t = 0; t < TT; ++t) {
    float w = wx[t];
    p0 += xb[t * NN + tid] * w;
    p1 += xb[t * NN + 256 + tid] * w;
  }

  const int lane = tid & 63, wv = tid >> 6;
  float m = fmaxf(p0, p1);
  #pragma unroll
  for (int o = 32; o; o >>= 1) m = fmaxf(m, __shfl_xor(m, o));
  if (lane == 0) red[wv] = m;
  __syncthreads();
  m = fmaxf(fmaxf(red[0], red[1]), fmaxf(red[2], red[3]));
  float e0 = expf(p0 - m), e1 = expf(p1 - m);
  float s = e0 + e1;
  #pragma unroll
  for (int o = 32; o; o >>= 1) s += __shfl_xor(s, o);
  if (lane == 0) red[4 + wv] = s;
  __syncthreads();
  s = red[4] + red[5] + red[6] + red[7];
  float inv = 1.0f / s;
  float a0 = e0 * inv, a1 = e1 * inv;
  a_out[b * NN + tid] = a0;
  a_out[b * NN + 256 + tid] = a1;
  as[tid] = a0;
  as[tid + 256] = a1;
  __syncthreads();

  // pass 2: ax = bf16(a * x), thread covers n = 2*tid, 2*tid+1 per row
  const float aa0 = as[tid * 2], aa1 = as[tid * 2 + 1];
  ushort* axb = ax + (size_t)b * TT * NN;
  for (int t = 0; t < TT; ++t) {
    const float2 xv = *(const float2*)(xb + t * NN + tid * 2);
    *(uint*)(axb + t * NN + tid * 2) = pk2(aa0 * xv.x, aa1 * xv.y);
  }
}

// ---------------------------------------------------------------------------
// Final: broadcast a over t into the attentions output (after the scan has
// finished reading the borrowed ax region).
// ---------------------------------------------------------------------------
__global__ __launch_bounds__(256) void bcast_kernel(
    const float* __restrict__ a, float* __restrict__ attn_out) {
  const size_t idx = (size_t)blockIdx.x * 256 + threadIdx.x;  // over B*T*N/4
  const int n4 = (int)(idx & 127);
  const int t = (int)((idx >> 7) & 255);
  const int b = (int)(idx >> 15);
  const float4 v = *(const float4*)(a + b * NN + n4 * 4);
  *(float4*)(attn_out + (((size_t)b * TT + t) * NN + n4 * 4)) = v;
}

// ---------------------------------------------------------------------------
// Persistent LSTM v5. 256 blocks (bg = blockIdx&15 -> one XCD per group),
// 512 threads (8 waves). W2 register-resident (A-operand, swapped). Per-lane
// in-register LSTM cell (D gives all 4 gates of one (batch,col) per lane).
// Changes vs v4: bar counters padded 256B (kill MALL line contention);
// h exchanged as packed bf16x2 (uint), producer packs via one shfl_xor;
// A-panel x-half loads pre-packed bf16 ax (no conversion VALU);
// per-wave arrive (target 128/step); 2 barriers/step.
// ---------------------------------------------------------------------------
__global__ __launch_bounds__(512, 2) void lstm_persistent(
    const ushort* __restrict__ ax,   // (B,T,N) bf16 = a*x
    const ushort* __restrict__ W2,   // (2048,1024) bf16
    const float* __restrict__ bgate, // (2048)
    const float* __restrict__ c0,    // (B,H)
    uint* __restrict__ hx16a, uint* __restrict__ hx16b,  // (B, H/2) bf16x2
    float* __restrict__ enc,         // (B,T,H)
    unsigned* __restrict__ bar) {
  __shared__ ushort hx[16 * 1024];  // 32 KB panel [16 batch][1024 k], swizzled

  const int tid = threadIdx.x;
  const int lane = tid & 63;
  const int w = tid >> 6;           // wave 0..7
  const int bg = blockIdx.x & 15;   // XCD-local group
  const int jt = blockIdx.x >> 4;   // col tile 0..15
  const int gb0 = bg * 16;
  unsigned* const barp = bar + bg * 64;  // 256B-padded counter

  // ---- register-resident W2 A-fragments: wave's 16 rows, r->(gate=r&3,kq=r>>2)
  short8 afrag[32];
  {
    const int r = lane & 15;
    const int grow = (r & 3) * 512 + jt * 32 + w * 4 + (r >> 2);
    const ushort* wp = W2 + (size_t)grow * 1024 + ((lane >> 4) << 3);
    #pragma unroll
    for (int ks = 0; ks < 32; ++ks)
      afrag[ks] = *(const short8*)(wp + ks * 32);
  }

  // ---- staging geometry: thread = (srow 0..15, sl 0..31)
  const int srow = tid >> 5;
  const int sl = tid & 31;
  const int r7 = srow & 7;

  // ---- per-lane output geometry: (batch eb, col ecol), 4 gates in acc[0..3]
  const int eb = lane & 15;
  const int kq = lane >> 4;
  const int ecol = jt * 32 + w * 4 + kq;
  const float bgi = bgate[ecol];
  const float bgf = bgate[512 + ecol];
  const float bgg = bgate[1024 + ecol];
  const float bgo = bgate[1536 + ecol];
  float c_reg = c0[(size_t)(gb0 + eb) * HH + ecol];

  // ---- MFMA B-read geometry (same swizzle as staging)
  const int bbase = (lane & 15) * 1024;
  const int br7 = (lane & 15) & 7;

  for (int t = 0; t < TT; ++t) {
    const uint* hin = (t & 1) ? hx16b : hx16a;
    uint* hout = (t & 1) ? hx16a : hx16b;

    // ---- stage x-part: pre-packed bf16, pure load->LDS
    {
      const ushort* axp = ax + ((size_t)(gb0 + srow) * TT + t) * NN;
      const uint4 p0 = *(const uint4*)(axp + sl * 8);
      const uint4 p1 = *(const uint4*)(axp + 256 + sl * 8);
      *(uint4*)&hx[srow * 1024 + ((sl ^ r7) << 3)] = p0;
      *(uint4*)&hx[srow * 1024 + (((32 + sl) ^ r7) << 3)] = p1;
    }

    // ---- per-wave poll: lane 0 spins (exec-masked), wave held together
    if (t) {
      if (lane == 0) {
        const unsigned target = 128u * (unsigned)t;
        while (__hip_atomic_load(barp, __ATOMIC_RELAXED,
                                 __HIP_MEMORY_SCOPE_AGENT) < target)
          __builtin_amdgcn_s_sleep(2);
      }
      asm volatile("" ::: "memory");  // keep h loads below the poll
    }

    // ---- stage h-part: packed bf16x2 agent-scope loads, no conversion
    {
      const uint* hrow = hin + (size_t)(gb0 + srow) * 256;
      const u64 q0 = __hip_atomic_load((const u64*)(hrow + sl * 4),
                                       __ATOMIC_RELAXED, __HIP_MEMORY_SCOPE_AGENT);
      const u64 q1 = __hip_atomic_load((const u64*)(hrow + sl * 4 + 2),
                                       __ATOMIC_RELAXED, __HIP_MEMORY_SCOPE_AGENT);
      const u64 q2 = __hip_atomic_load((const u64*)(hrow + 128 + sl * 4),
                                       __ATOMIC_RELAXED, __HIP_MEMORY_SCOPE_AGENT);
      const u64 q3 = __hip_atomic_load((const u64*)(hrow + 128 + sl * 4 + 2),
                                       __ATOMIC_RELAXED, __HIP_MEMORY_SCOPE_AGENT);
      uint4 p0, p1;
      p0.x = (uint)q0; p0.y = (uint)(q0 >> 32);
      p0.z = (uint)q1; p0.w = (uint)(q1 >> 32);
      p1.x = (uint)q2; p1.y = (uint)(q2 >> 32);
      p1.z = (uint)q3; p1.w = (uint)(q3 >> 32);
      *(uint4*)&hx[srow * 1024 + (((64 + sl) ^ r7) << 3)] = p0;
      *(uint4*)&hx[srow * 1024 + (((96 + sl) ^ r7) << 3)] = p1;
    }
    __syncthreads();  // B1: panel complete

    // ---- full K=1024 GEMM: D[row=W2row][col=batch]
    f32x4 acc = {0.f, 0.f, 0.f, 0.f};
    #pragma unroll
    for (int ks = 0; ks < 32; ++ks) {
      const int ag = ks * 4 + kq;
      short8 bf = *(const short8*)&hx[bbase + ((ag ^ br7) << 3)];
      acc = __builtin_amdgcn_mfma_f32_16x16x32_bf16(afrag[ks], bf, acc, 0, 0, 0);
    }
    __syncthreads();  // B2: all LDS reads done; next-step writes may begin

    // ---- in-lane LSTM cell; pack h pairs; per-wave signal
    {
      const float ig = sigmoidf_(acc[0] + bgi);
      const float fg = sigmoidf_(acc[1] + bgf);
      const float gg = tanhf(acc[2] + bgg);
      const float og = sigmoidf_(acc[3] + bgo);
      const float cn = fg * c_reg + ig * gg;
      const float hn = og * tanhf(cn);
      c_reg = cn;
      const float hp_ = __shfl_xor(hn, 16);   // partner col (kq^1)
      if (!(lane & 16)) {                     // kq even lanes store the pair
        __hip_atomic_store(hout + (size_t)(gb0 + eb) * 256 + (ecol >> 1),
                           pk2(hn, hp_),
                           __ATOMIC_RELAXED, __HIP_MEMORY_SCOPE_AGENT);
      }
      asm volatile("s_waitcnt vmcnt(0)" ::: "memory");  // wave's h at MALL
      if (lane == 0)
        __hip_atomic_fetch_add(barp, 1u, __ATOMIC_RELAXED,
                               __HIP_MEMORY_SCOPE_AGENT);
      enc[((size_t)(gb0 + eb) * TT + t) * HH + ecol] = hn;  // off critical path
    }
  }
}

extern "C" void kernel_launch(void* const* d_in, const int* in_sizes, int n_in,
                              void* d_out, int out_size, void* d_ws, size_t ws_size,
                              hipStream_t stream) {
  const float* x      = (const float*)d_in[0];
  const float* h0     = (const float*)d_in[1];
  const float* c0     = (const float*)d_in[2];
  const float* attn_w = (const float*)d_in[3];
  // d_in[4] = attn_b: softmax-shift-invariant -> unused
  const float* w_ih   = (const float*)d_in[5];
  const float* w_hh   = (const float*)d_in[6];
  const float* b_ih   = (const float*)d_in[7];
  const float* b_hh   = (const float*)d_in[8];

  float* attn_out = (float*)d_out;                         // (B,T,N)
  float* enc_out  = (float*)d_out + (size_t)BB * TT * NN;  // (B,T,H)
  // borrow the attn output region for bf16 ax (64 MB of 128 MB) until bcast
  ushort* ax = (ushort*)d_out;

  char* ws = (char*)d_ws;
  float*    a_ws  = (float*)(ws);                    // 512 KB
  ushort*   W2_ws = (ushort*)(ws + 0x80000);         // 4 MB
  float*    bg_ws = (float*)(ws + 0x480000);         // 8 KB
  uint*     hx16a = (uint*)(ws + 0x482000);          // 256 KB
  uint*     hx16b = (uint*)(ws + 0x4C2000);          // 256 KB
  unsigned* bar   = (unsigned*)(ws + 0x502000);      // 4 KB (16 x 256B)

  prep_kernel<<<8192, 256, 0, stream>>>(w_ih, w_hh, b_ih, b_hh, h0,
                                        W2_ws, bg_ws, hx16a, bar);
  attn_kernel<<<BB, 256, 0, stream>>>(x, attn_w, a_ws, ax);

  {
    dim3 grid(256), block(512);
    void* args[] = {(void*)&ax, (void*)&W2_ws, (void*)&bg_ws, (void*)&c0,
                    (void*)&hx16a, (void*)&hx16b, (void*)&enc_out,
                    (void*)&bar};
    hipLaunchCooperativeKernel((void*)lstm_persistent, grid, block, args, 0,
                               stream);
  }

  bcast_kernel<<<32768, 256, 0, stream>>>(a_ws, attn_out);
}

// Round 8
// 1143.729 us; speedup vs baseline: 7.4568x; 1.0020x over previous
//
#include <hip/hip_runtime.h>

#define BB 256
#define TT 256
#define NN 512
#define HH 512

typedef short short8 __attribute__((ext_vector_type(8)));
typedef float f32x4 __attribute__((ext_vector_type(4)));
typedef unsigned long long u64;

static __device__ __forceinline__ ushort f2bf(float f) {
  uint b = __builtin_bit_cast(uint, f);
  b += 0x7FFFu + ((b >> 16) & 1u);
  return (ushort)(b >> 16);
}
static __device__ __forceinline__ uint pk2(float lo, float hi) {
  return (uint)f2bf(lo) | ((uint)f2bf(hi) << 16);
}
// exp2-based activations: single v_exp_f32
static __device__ __forceinline__ float sigm_(float x) {
  return 1.0f / (1.0f + exp2f(-1.4426950408889634f * x));
}
static __device__ __forceinline__ float tanh_(float x) {
  return 2.0f / (1.0f + exp2f(-2.8853900817779268f * x)) - 1.0f;
}

// ---------------------------------------------------------------------------
// Prep: W2 = [w_ih | w_hh] bf16 (2048 x 1024), b_gate = b_ih + b_hh,
// h0 packed bf16x2 -> hx16a, zero padded barrier counters (every launch).
// ---------------------------------------------------------------------------
__global__ __launch_bounds__(256) void prep_kernel(
    const float* __restrict__ w_ih, const float* __restrict__ w_hh,
    const float* __restrict__ b_ih, const float* __restrict__ b_hh,
    const float* __restrict__ h0,
    ushort* __restrict__ W2, float* __restrict__ bgate,
    uint* __restrict__ hx16a, unsigned* __restrict__ bar) {
  int idx = blockIdx.x * 256 + threadIdx.x;
  if (idx < 2048 * 1024) {
    int row = idx >> 10;
    int k = idx & 1023;
    float v = (k < NN) ? w_ih[row * NN + k] : w_hh[row * HH + (k - NN)];
    W2[idx] = f2bf(v);
  }
  if (idx < 2048) bgate[idx] = b_ih[idx] + b_hh[idx];
  if (idx < BB * HH / 2) hx16a[idx] = pk2(h0[2 * idx], h0[2 * idx + 1]);
  if (idx < 16 * 64) bar[idx] = 0u;
}

// ---------------------------------------------------------------------------
// Attention + ax precompute (a = softmax_n(proj_x), timestep-invariant by
// softmax shift invariance). Pass 2 writes bf16 ax into the borrowed
// attentions output region; attn_out itself written by bcast_kernel.
// ---------------------------------------------------------------------------
__global__ __launch_bounds__(256) void attn_kernel(
    const float* __restrict__ x, const float* __restrict__ attn_w,
    float* __restrict__ a_out, ushort* __restrict__ ax) {
  __shared__ float wx[TT];
  __shared__ float as[NN];
  __shared__ float red[8];
  const int b = blockIdx.x;
  const int tid = threadIdx.x;
  wx[tid] = attn_w[2 * HH + tid];
  __syncthreads();

  const float* xb = x + (size_t)b * TT * NN;
  float p0 = 0.0f, p1 = 0.0f;
  for (int t = 0; t < TT; ++t) {
    float w = wx[t];
    p0 += xb[t * NN + tid] * w;
    p1 += xb[t * NN + 256 + tid] * w;
  }

  const int lane = tid & 63, wv = tid >> 6;
  float m = fmaxf(p0, p1);
  #pragma unroll
  for (int o = 32; o; o >>= 1) m = fmaxf(m, __shfl_xor(m, o));
  if (lane == 0) red[wv] = m;
  __syncthreads();
  m = fmaxf(fmaxf(red[0], red[1]), fmaxf(red[2], red[3]));
  float e0 = expf(p0 - m), e1 = expf(p1 - m);
  float s = e0 + e1;
  #pragma unroll
  for (int o = 32; o; o >>= 1) s += __shfl_xor(s, o);
  if (lane == 0) red[4 + wv] = s;
  __syncthreads();
  s = red[4] + red[5] + red[6] + red[7];
  float inv = 1.0f / s;
  float a0 = e0 * inv, a1 = e1 * inv;
  a_out[b * NN + tid] = a0;
  a_out[b * NN + 256 + tid] = a1;
  as[tid] = a0;
  as[tid + 256] = a1;
  __syncthreads();

  const float aa0 = as[tid * 2], aa1 = as[tid * 2 + 1];
  ushort* axb = ax + (size_t)b * TT * NN;
  for (int t = 0; t < TT; ++t) {
    const float2 xv = *(const float2*)(xb + t * NN + tid * 2);
    *(uint*)(axb + t * NN + tid * 2) = pk2(aa0 * xv.x, aa1 * xv.y);
  }
}

// ---------------------------------------------------------------------------
// Final: broadcast a over t into the attentions output.
// ---------------------------------------------------------------------------
__global__ __launch_bounds__(256) void bcast_kernel(
    const float* __restrict__ a, float* __restrict__ attn_out) {
  const size_t idx = (size_t)blockIdx.x * 256 + threadIdx.x;
  const int n4 = (int)(idx & 127);
  const int t = (int)((idx >> 7) & 255);
  const int b = (int)(idx >> 15);
  const float4 v = *(const float4*)(a + b * NN + n4 * 4);
  *(float4*)(attn_out + (((size_t)b * TT + t) * NN + n4 * 4)) = v;
}

// ---------------------------------------------------------------------------
// Persistent LSTM v8 = v5 EXACTLY (proven sync + proven per-iteration XOR
// B-read addressing) + two safe changes:
//  * W2 A-fragments pinned in VGPRs via asm (uniform areg[i] = chunk i --
//    NO per-lane XOR preload: round-6/7 failure root-caused to per-lane
//    chunk permutation breaking MFMA's cross-lane k-consistency; the A/B
//    chunk pairing must be uniform per INSTRUCTION, not per lane).
//  * exp2-based sigmoid/tanh.
// Cross-block h + barrier remain RELAXED agent atomics (no cache flushes).
// ---------------------------------------------------------------------------
__global__ __launch_bounds__(512, 2) void lstm_persistent(
    const ushort* __restrict__ ax,   // (B,T,N) bf16 = a*x
    const ushort* __restrict__ W2,   // (2048,1024) bf16
    const float* __restrict__ bgate, // (2048)
    const float* __restrict__ c0,    // (B,H)
    uint* __restrict__ hx16a, uint* __restrict__ hx16b,  // (B, H/2) bf16x2
    float* __restrict__ enc,         // (B,T,H)
    unsigned* __restrict__ bar) {
  __shared__ ushort hx[16 * 1024];  // 32 KB panel [16 batch][1024 k], swizzled

  const int tid = threadIdx.x;
  const int lane = tid & 63;
  const int w = tid >> 6;
  const int bg = blockIdx.x & 15;   // XCD-local group
  const int jt = blockIdx.x >> 4;
  const int gb0 = bg * 16;
  unsigned* const barp = bar + bg * 64;  // 256B-padded counter

  // ---- W2 A-fragments: areg[i] = k-chunk i (UNIFORM across lanes), pinned
  f32x4 areg[32];
  {
    const int r = lane & 15;
    const int grow = (r & 3) * 512 + jt * 32 + w * 4 + (r >> 2);
    const ushort* wp = W2 + (size_t)grow * 1024 + ((lane >> 4) << 3);
    #pragma unroll
    for (int i = 0; i < 32; ++i) {
      areg[i] = *(const f32x4*)(wp + (i << 5));
      asm volatile("" : "+v"(areg[i]));  // force residency across the t-loop
    }
  }

  // ---- staging geometry: thread = (srow 0..15, sl 0..31)
  const int srow = tid >> 5;
  const int sl = tid & 31;
  const int r7 = srow & 7;

  // ---- per-lane output geometry: (batch eb, col ecol), 4 gates in acc[0..3]
  const int eb = lane & 15;
  const int kq = lane >> 4;
  const int ecol = jt * 32 + w * 4 + kq;
  const float bgi = bgate[ecol];
  const float bgf = bgate[512 + ecol];
  const float bgg = bgate[1024 + ecol];
  const float bgo = bgate[1536 + ecol];
  float c_reg = c0[(size_t)(gb0 + eb) * HH + ecol];

  // ---- MFMA B-read geometry (v5's proven per-iteration XOR addressing)
  const int bbase = (lane & 15) * 1024;
  const int br7 = (lane & 15) & 7;

  for (int t = 0; t < TT; ++t) {
    const uint* hin = (t & 1) ? hx16b : hx16a;
    uint* hout = (t & 1) ? hx16a : hx16b;

    // ---- stage x-part: pre-packed bf16, pure load->LDS
    {
      const ushort* axp = ax + ((size_t)(gb0 + srow) * TT + t) * NN;
      const uint4 p0 = *(const uint4*)(axp + sl * 8);
      const uint4 p1 = *(const uint4*)(axp + 256 + sl * 8);
      *(uint4*)&hx[srow * 1024 + ((sl ^ r7) << 3)] = p0;
      *(uint4*)&hx[srow * 1024 + (((32 + sl) ^ r7) << 3)] = p1;
    }

    // ---- per-wave poll: lane 0 spins (exec-masked), wave held together
    if (t) {
      if (lane == 0) {
        const unsigned target = 128u * (unsigned)t;
        while (__hip_atomic_load(barp, __ATOMIC_RELAXED,
                                 __HIP_MEMORY_SCOPE_AGENT) < target)
          __builtin_amdgcn_s_sleep(2);
      }
      asm volatile("" ::: "memory");  // keep h loads below the poll
    }

    // ---- stage h-part: packed bf16x2 agent-scope loads
    {
      const uint* hrow = hin + (size_t)(gb0 + srow) * 256;
      const u64 q0 = __hip_atomic_load((const u64*)(hrow + sl * 4),
                                       __ATOMIC_RELAXED, __HIP_MEMORY_SCOPE_AGENT);
      const u64 q1 = __hip_atomic_load((const u64*)(hrow + sl * 4 + 2),
                                       __ATOMIC_RELAXED, __HIP_MEMORY_SCOPE_AGENT);
      const u64 q2 = __hip_atomic_load((const u64*)(hrow + 128 + sl * 4),
                                       __ATOMIC_RELAXED, __HIP_MEMORY_SCOPE_AGENT);
      const u64 q3 = __hip_atomic_load((const u64*)(hrow + 128 + sl * 4 + 2),
                                       __ATOMIC_RELAXED, __HIP_MEMORY_SCOPE_AGENT);
      uint4 p0, p1;
      p0.x = (uint)q0; p0.y = (uint)(q0 >> 32);
      p0.z = (uint)q1; p0.w = (uint)(q1 >> 32);
      p1.x = (uint)q2; p1.y = (uint)(q2 >> 32);
      p1.z = (uint)q3; p1.w = (uint)(q3 >> 32);
      *(uint4*)&hx[srow * 1024 + (((64 + sl) ^ r7) << 3)] = p0;
      *(uint4*)&hx[srow * 1024 + (((96 + sl) ^ r7) << 3)] = p1;
    }
    __syncthreads();  // B1: full panel ready

    // ---- full K=1024 GEMM: at iteration ks, EVERY lane supplies logical
    // chunk ks for both A (areg[ks]) and B (XOR-compensated read)
    f32x4 acc = {0.f, 0.f, 0.f, 0.f};
    #pragma unroll
    for (int ks = 0; ks < 32; ++ks) {
      const int ag = ks * 4 + kq;
      const short8 bf = *(const short8*)&hx[bbase + ((ag ^ br7) << 3)];
      acc = __builtin_amdgcn_mfma_f32_16x16x32_bf16(
          __builtin_bit_cast(short8, areg[ks]), bf, acc, 0, 0, 0);
    }
    __syncthreads();  // B2: all LDS reads done; next-step writes may begin

    // ---- in-lane LSTM cell; pack h pairs; per-wave arrive (v5 structure)
    {
      const float ig = sigm_(acc[0] + bgi);
      const float fg = sigm_(acc[1] + bgf);
      const float gg = tanh_(acc[2] + bgg);
      const float og = sigm_(acc[3] + bgo);
      const float cn = fg * c_reg + ig * gg;
      const float hn = og * tanh_(cn);
      c_reg = cn;
      const float hp_ = __shfl_xor(hn, 16);   // partner col (kq^1)
      if (!(lane & 16)) {                     // kq even lanes store the pair
        __hip_atomic_store(hout + (size_t)(gb0 + eb) * 256 + (ecol >> 1),
                           pk2(hn, hp_),
                           __ATOMIC_RELAXED, __HIP_MEMORY_SCOPE_AGENT);
      }
      asm volatile("s_waitcnt vmcnt(0)" ::: "memory");  // wave's h at MALL
      if (lane == 0)
        __hip_atomic_fetch_add(barp, 1u, __ATOMIC_RELAXED,
                               __HIP_MEMORY_SCOPE_AGENT);
      enc[((size_t)(gb0 + eb) * TT + t) * HH + ecol] = hn;  // off critical path
    }
  }
}

extern "C" void kernel_launch(void* const* d_in, const int* in_sizes, int n_in,
                              void* d_out, int out_size, void* d_ws, size_t ws_size,
                              hipStream_t stream) {
  const float* x      = (const float*)d_in[0];
  const float* h0     = (const float*)d_in[1];
  const float* c0     = (const float*)d_in[2];
  const float* attn_w = (const float*)d_in[3];
  // d_in[4] = attn_b: softmax-shift-invariant -> unused
  const float* w_ih   = (const float*)d_in[5];
  const float* w_hh   = (const float*)d_in[6];
  const float* b_ih   = (const float*)d_in[7];
  const float* b_hh   = (const float*)d_in[8];

  float* attn_out = (float*)d_out;                         // (B,T,N)
  float* enc_out  = (float*)d_out + (size_t)BB * TT * NN;  // (B,T,H)
  // borrow the attn output region for bf16 ax (64 MB of 128 MB) until bcast
  ushort* ax = (ushort*)d_out;

  char* ws = (char*)d_ws;
  float*    a_ws  = (float*)(ws);                    // 512 KB
  ushort*   W2_ws = (ushort*)(ws + 0x80000);         // 4 MB
  float*    bg_ws = (float*)(ws + 0x480000);         // 8 KB
  uint*     hx16a = (uint*)(ws + 0x482000);          // 256 KB
  uint*     hx16b = (uint*)(ws + 0x4C2000);          // 256 KB
  unsigned* bar   = (unsigned*)(ws + 0x502000);      // 4 KB (16 x 256B)

  prep_kernel<<<8192, 256, 0, stream>>>(w_ih, w_hh, b_ih, b_hh, h0,
                                        W2_ws, bg_ws, hx16a, bar);
  attn_kernel<<<BB, 256, 0, stream>>>(x, attn_w, a_ws, ax);

  {
    dim3 grid(256), block(512);
    void* args[] = {(void*)&ax, (void*)&W2_ws, (void*)&bg_ws, (void*)&c0,
                    (void*)&hx16a, (void*)&hx16b, (void*)&enc_out,
                    (void*)&bar};
    hipLaunchCooperativeKernel((void*)lstm_persistent, grid, block, args, 0,
                               stream);
  }

  bcast_kernel<<<32768, 256, 0, stream>>>(a_ws, attn_out);
}

// Round 9
// 855.210 us; speedup vs baseline: 9.9725x; 1.3374x over previous
//
#include <hip/hip_runtime.h>

#define BB 256
#define TT 256
#define NN 512
#define HH 512

typedef short short8 __attribute__((ext_vector_type(8)));
typedef float f32x4 __attribute__((ext_vector_type(4)));
typedef unsigned long long u64;

static __device__ __forceinline__ ushort f2bf(float f) {
  uint b = __builtin_bit_cast(uint, f);
  b += 0x7FFFu + ((b >> 16) & 1u);
  return (ushort)(b >> 16);
}
static __device__ __forceinline__ uint pk2(float lo, float hi) {
  return (uint)f2bf(lo) | ((uint)f2bf(hi) << 16);
}
static __device__ __forceinline__ float sigm_(float x) {
  return 1.0f / (1.0f + exp2f(-1.4426950408889634f * x));
}
static __device__ __forceinline__ float tanh_(float x) {
  return 2.0f / (1.0f + exp2f(-2.8853900817779268f * x)) - 1.0f;
}

// ---------------------------------------------------------------------------
// Prep: W2 = [w_ih | w_hh] bf16 (2048 x 1024), b_gate = b_ih + b_hh,
// h0 packed bf16x2 -> hx16a, zero padded barrier counters (every launch).
// ---------------------------------------------------------------------------
__global__ __launch_bounds__(256) void prep_kernel(
    const float* __restrict__ w_ih, const float* __restrict__ w_hh,
    const float* __restrict__ b_ih, const float* __restrict__ b_hh,
    const float* __restrict__ h0,
    ushort* __restrict__ W2, float* __restrict__ bgate,
    uint* __restrict__ hx16a, unsigned* __restrict__ bar) {
  int idx = blockIdx.x * 256 + threadIdx.x;
  if (idx < 2048 * 1024) {
    int row = idx >> 10;
    int k = idx & 1023;
    float v = (k < NN) ? w_ih[row * NN + k] : w_hh[row * HH + (k - NN)];
    W2[idx] = f2bf(v);
  }
  if (idx < 2048) bgate[idx] = b_ih[idx] + b_hh[idx];
  if (idx < BB * HH / 2) hx16a[idx] = pk2(h0[2 * idx], h0[2 * idx + 1]);
  if (idx < 16 * 64) bar[idx] = 0u;
}

// ---------------------------------------------------------------------------
// Attention + ax precompute (a = softmax_n(proj_x), timestep-invariant by
// softmax shift invariance). Pass 2 writes bf16 ax into the borrowed
// attentions output region; attn_out itself written by bcast_kernel.
// ---------------------------------------------------------------------------
__global__ __launch_bounds__(256) void attn_kernel(
    const float* __restrict__ x, const float* __restrict__ attn_w,
    float* __restrict__ a_out, ushort* __restrict__ ax) {
  __shared__ float wx[TT];
  __shared__ float as[NN];
  __shared__ float red[8];
  const int b = blockIdx.x;
  const int tid = threadIdx.x;
  wx[tid] = attn_w[2 * HH + tid];
  __syncthreads();

  const float* xb = x + (size_t)b * TT * NN;
  float p0 = 0.0f, p1 = 0.0f;
  for (int t = 0; t < TT; ++t) {
    float w = wx[t];
    p0 += xb[t * NN + tid] * w;
    p1 += xb[t * NN + 256 + tid] * w;
  }

  const int lane = tid & 63, wv = tid >> 6;
  float m = fmaxf(p0, p1);
  #pragma unroll
  for (int o = 32; o; o >>= 1) m = fmaxf(m, __shfl_xor(m, o));
  if (lane == 0) red[wv] = m;
  __syncthreads();
  m = fmaxf(fmaxf(red[0], red[1]), fmaxf(red[2], red[3]));
  float e0 = expf(p0 - m), e1 = expf(p1 - m);
  float s = e0 + e1;
  #pragma unroll
  for (int o = 32; o; o >>= 1) s += __shfl_xor(s, o);
  if (lane == 0) red[4 + wv] = s;
  __syncthreads();
  s = red[4] + red[5] + red[6] + red[7];
  float inv = 1.0f / s;
  float a0 = e0 * inv, a1 = e1 * inv;
  a_out[b * NN + tid] = a0;
  a_out[b * NN + 256 + tid] = a1;
  as[tid] = a0;
  as[tid + 256] = a1;
  __syncthreads();

  const float aa0 = as[tid * 2], aa1 = as[tid * 2 + 1];
  ushort* axb = ax + (size_t)b * TT * NN;
  for (int t = 0; t < TT; ++t) {
    const float2 xv = *(const float2*)(xb + t * NN + tid * 2);
    *(uint*)(axb + t * NN + tid * 2) = pk2(aa0 * xv.x, aa1 * xv.y);
  }
}

// ---------------------------------------------------------------------------
// Final: broadcast a over t into the attentions output.
// ---------------------------------------------------------------------------
__global__ __launch_bounds__(256) void bcast_kernel(
    const float* __restrict__ a, float* __restrict__ attn_out) {
  const size_t idx = (size_t)blockIdx.x * 256 + threadIdx.x;
  const int n4 = (int)(idx & 127);
  const int t = (int)((idx >> 7) & 255);
  const int b = (int)(idx >> 15);
  const float4 v = *(const float4*)(a + b * NN + n4 * 4);
  *(float4*)(attn_out + (((size_t)b * TT + t) * NN + n4 * 4)) = v;
}

// ---------------------------------------------------------------------------
// Persistent LSTM v9 = v8 data path (proven) + Group-B sync restructure
// (exonerated: v6/v7 bit-identical failures root-caused to the Group-A XOR
// preload, which is NOT present here):
//  * single global poller per block (tid0) + LDS step_flag broadcast
//    -> 16 MALL pollers per bg instead of 128.
//  * combined arrive: per-wave vmcnt drain -> LDS ds_add; 8th wave does the
//    ONE global add -> 16 MALL RMWs per bg-step instead of 128 (kills the
//    barrier-line serialization, the main suspect for the 2.3x chain gap).
//  * x-half MFMAs run under the poll (x has no h dependency).
//  * x global loads for t+1 prefetched into registers during step t.
// Cross-block h + barrier remain RELAXED agent atomics (no cache flushes).
// ---------------------------------------------------------------------------
__global__ __launch_bounds__(512, 2) void lstm_persistent(
    const ushort* __restrict__ ax,   // (B,T,N) bf16 = a*x
    const ushort* __restrict__ W2,   // (2048,1024) bf16
    const float* __restrict__ bgate, // (2048)
    const float* __restrict__ c0,    // (B,H)
    uint* __restrict__ hx16a, uint* __restrict__ hx16b,  // (B, H/2) bf16x2
    float* __restrict__ enc,         // (B,T,H)
    unsigned* __restrict__ bar) {
  __shared__ ushort hx[16 * 1024];  // 32 KB panel [16 batch][1024 k], swizzled
  __shared__ unsigned warr;         // monotonic wave-arrive counter
  __shared__ unsigned step_flag;    // poll broadcast (monotonic)

  const int tid = threadIdx.x;
  const int lane = tid & 63;
  const int w = tid >> 6;
  const int bg = blockIdx.x & 15;   // XCD-local group
  const int jt = blockIdx.x >> 4;
  const int gb0 = bg * 16;
  unsigned* const barp = bar + bg * 64;  // 256B-padded counter

  if (tid == 0) { warr = 0u; step_flag = 0u; }

  // ---- W2 A-fragments: areg[i] = k-chunk i (uniform across lanes)
  f32x4 areg[32];
  {
    const int r = lane & 15;
    const int grow = (r & 3) * 512 + jt * 32 + w * 4 + (r >> 2);
    const ushort* wp = W2 + (size_t)grow * 1024 + ((lane >> 4) << 3);
    #pragma unroll
    for (int i = 0; i < 32; ++i) {
      areg[i] = *(const f32x4*)(wp + (i << 5));
      asm volatile("" : "+v"(areg[i]));
    }
  }

  // ---- staging geometry: thread = (srow 0..15, sl 0..31)
  const int srow = tid >> 5;
  const int sl = tid & 31;
  const int r7 = srow & 7;

  // ---- per-lane output geometry: (batch eb, col ecol), 4 gates in acc[0..3]
  const int eb = lane & 15;
  const int kq = lane >> 4;
  const int ecol = jt * 32 + w * 4 + kq;
  const float bgi = bgate[ecol];
  const float bgf = bgate[512 + ecol];
  const float bgg = bgate[1024 + ecol];
  const float bgo = bgate[1536 + ecol];
  float c_reg = c0[(size_t)(gb0 + eb) * HH + ecol];

  // ---- MFMA B-read geometry (v5/v8 proven per-iteration XOR addressing)
  const int bbase = (lane & 15) * 1024;
  const int br7 = (lane & 15) & 7;

  // ---- x prefetch for t=0
  uint4 px0, px1;
  {
    const ushort* axp = ax + ((size_t)(gb0 + srow) * TT + 0) * NN;
    px0 = *(const uint4*)(axp + sl * 8);
    px1 = *(const uint4*)(axp + 256 + sl * 8);
  }

  for (int t = 0; t < TT; ++t) {
    const uint* hin = (t & 1) ? hx16b : hx16a;
    uint* hout = (t & 1) ? hx16a : hx16b;

    // ---- stage x-part from prefetch regs; issue prefetch for t+1
    *(uint4*)&hx[srow * 1024 + ((sl ^ r7) << 3)] = px0;
    *(uint4*)&hx[srow * 1024 + (((32 + sl) ^ r7) << 3)] = px1;
    if (t + 1 < TT) {
      const ushort* axp = ax + ((size_t)(gb0 + srow) * TT + (t + 1)) * NN;
      px0 = *(const uint4*)(axp + sl * 8);
      px1 = *(const uint4*)(axp + 256 + sl * 8);
    }
    __syncthreads();  // B1: x-panel ready

    // ---- single poller (wave0 holds on lane0's loop), flag broadcast
    if (t && w == 0) {
      if (lane == 0) {
        const unsigned target = 16u * (unsigned)t;
        while (__hip_atomic_load(barp, __ATOMIC_RELAXED,
                                 __HIP_MEMORY_SCOPE_AGENT) < target)
          __builtin_amdgcn_s_sleep(1);
        __hip_atomic_store(&step_flag, (unsigned)t, __ATOMIC_RELEASE,
                           __HIP_MEMORY_SCOPE_WORKGROUP);
      }
    }

    // ---- x-half MFMAs (no h dependency) run under the poll
    f32x4 acc = {0.f, 0.f, 0.f, 0.f};
    #pragma unroll
    for (int ks = 0; ks < 16; ++ks) {
      const int ag = ks * 4 + kq;
      const short8 bf = *(const short8*)&hx[bbase + ((ag ^ br7) << 3)];
      acc = __builtin_amdgcn_mfma_f32_16x16x32_bf16(
          __builtin_bit_cast(short8, areg[ks]), bf, acc, 0, 0, 0);
    }

    // ---- waves 1..7 wait for the broadcast flag (whole wave holds on lane0)
    if (t && w != 0) {
      if (lane == 0) {
        while (__hip_atomic_load(&step_flag, __ATOMIC_ACQUIRE,
                                 __HIP_MEMORY_SCOPE_WORKGROUP) < (unsigned)t) {}
      }
    }
    asm volatile("" ::: "memory");  // keep h loads below the gate

    // ---- stage h-part: packed bf16x2 agent-scope loads
    {
      const uint* hrow = hin + (size_t)(gb0 + srow) * 256;
      const u64 q0 = __hip_atomic_load((const u64*)(hrow + sl * 4),
                                       __ATOMIC_RELAXED, __HIP_MEMORY_SCOPE_AGENT);
      const u64 q1 = __hip_atomic_load((const u64*)(hrow + sl * 4 + 2),
                                       __ATOMIC_RELAXED, __HIP_MEMORY_SCOPE_AGENT);
      const u64 q2 = __hip_atomic_load((const u64*)(hrow + 128 + sl * 4),
                                       __ATOMIC_RELAXED, __HIP_MEMORY_SCOPE_AGENT);
      const u64 q3 = __hip_atomic_load((const u64*)(hrow + 128 + sl * 4 + 2),
                                       __ATOMIC_RELAXED, __HIP_MEMORY_SCOPE_AGENT);
      uint4 p0, p1;
      p0.x = (uint)q0; p0.y = (uint)(q0 >> 32);
      p0.z = (uint)q1; p0.w = (uint)(q1 >> 32);
      p1.x = (uint)q2; p1.y = (uint)(q2 >> 32);
      p1.z = (uint)q3; p1.w = (uint)(q3 >> 32);
      *(uint4*)&hx[srow * 1024 + (((64 + sl) ^ r7) << 3)] = p0;
      *(uint4*)&hx[srow * 1024 + (((96 + sl) ^ r7) << 3)] = p1;
    }
    __syncthreads();  // B2: h-panel ready

    // ---- h-half MFMAs
    #pragma unroll
    for (int ks = 16; ks < 32; ++ks) {
      const int ag = ks * 4 + kq;
      const short8 bf = *(const short8*)&hx[bbase + ((ag ^ br7) << 3)];
      acc = __builtin_amdgcn_mfma_f32_16x16x32_bf16(
          __builtin_bit_cast(short8, areg[ks]), bf, acc, 0, 0, 0);
    }

    // ---- in-lane LSTM cell; publish h; combined arrive
    {
      const float ig = sigm_(acc[0] + bgi);
      const float fg = sigm_(acc[1] + bgf);
      const float gg = tanh_(acc[2] + bgg);
      const float og = sigm_(acc[3] + bgo);
      const float cn = fg * c_reg + ig * gg;
      const float hn = og * tanh_(cn);
      c_reg = cn;
      const float hp_ = __shfl_xor(hn, 16);   // partner col (kq^1)
      if (!(lane & 16)) {                     // kq even lanes store the pair
        __hip_atomic_store(hout + (size_t)(gb0 + eb) * 256 + (ecol >> 1),
                           pk2(hn, hp_),
                           __ATOMIC_RELAXED, __HIP_MEMORY_SCOPE_AGENT);
      }
      asm volatile("s_waitcnt vmcnt(0)" ::: "memory");  // wave's h at MALL
      if (lane == 0) {
        const unsigned old = __hip_atomic_fetch_add(
            &warr, 1u, __ATOMIC_ACQ_REL, __HIP_MEMORY_SCOPE_WORKGROUP);
        if (old == 8u * (unsigned)t + 7u)     // last of 8 waves: one global add
          __hip_atomic_fetch_add(barp, 1u, __ATOMIC_RELAXED,
                                 __HIP_MEMORY_SCOPE_AGENT);
      }
      enc[((size_t)(gb0 + eb) * TT + t) * HH + ecol] = hn;  // off critical path
    }
  }
}

extern "C" void kernel_launch(void* const* d_in, const int* in_sizes, int n_in,
                              void* d_out, int out_size, void* d_ws, size_t ws_size,
                              hipStream_t stream) {
  const float* x      = (const float*)d_in[0];
  const float* h0     = (const float*)d_in[1];
  const float* c0     = (const float*)d_in[2];
  const float* attn_w = (const float*)d_in[3];
  // d_in[4] = attn_b: softmax-shift-invariant -> unused
  const float* w_ih   = (const float*)d_in[5];
  const float* w_hh   = (const float*)d_in[6];
  const float* b_ih   = (const float*)d_in[7];
  const float* b_hh   = (const float*)d_in[8];

  float* attn_out = (float*)d_out;                         // (B,T,N)
  float* enc_out  = (float*)d_out + (size_t)BB * TT * NN;  // (B,T,H)
  // borrow the attn output region for bf16 ax (64 MB of 128 MB) until bcast
  ushort* ax = (ushort*)d_out;

  char* ws = (char*)d_ws;
  float*    a_ws  = (float*)(ws);                    // 512 KB
  ushort*   W2_ws = (ushort*)(ws + 0x80000);         // 4 MB
  float*    bg_ws = (float*)(ws + 0x480000);         // 8 KB
  uint*     hx16a = (uint*)(ws + 0x482000);          // 256 KB
  uint*     hx16b = (uint*)(ws + 0x4C2000);          // 256 KB
  unsigned* bar   = (unsigned*)(ws + 0x502000);      // 4 KB (16 x 256B)

  prep_kernel<<<8192, 256, 0, stream>>>(w_ih, w_hh, b_ih, b_hh, h0,
                                        W2_ws, bg_ws, hx16a, bar);
  attn_kernel<<<BB, 256, 0, stream>>>(x, attn_w, a_ws, ax);

  {
    dim3 grid(256), block(512);
    void* args[] = {(void*)&ax, (void*)&W2_ws, (void*)&bg_ws, (void*)&c0,
                    (void*)&hx16a, (void*)&hx16b, (void*)&enc_out,
                    (void*)&bar};
    hipLaunchCooperativeKernel((void*)lstm_persistent, grid, block, args, 0,
                               stream);
  }

  bcast_kernel<<<32768, 256, 0, stream>>>(a_ws, attn_out);
}

// Round 10
// 835.532 us; speedup vs baseline: 10.2074x; 1.0236x over previous
//
#include <hip/hip_runtime.h>

#define BB 256
#define TT 256
#define NN 512
#define HH 512

typedef short short8 __attribute__((ext_vector_type(8)));
typedef float f32x4 __attribute__((ext_vector_type(4)));
typedef unsigned long long u64;

static __device__ __forceinline__ ushort f2bf(float f) {
  uint b = __builtin_bit_cast(uint, f);
  b += 0x7FFFu + ((b >> 16) & 1u);
  return (ushort)(b >> 16);
}
static __device__ __forceinline__ uint pk2(float lo, float hi) {
  return (uint)f2bf(lo) | ((uint)f2bf(hi) << 16);
}
static __device__ __forceinline__ float sigm_(float x) {
  return 1.0f / (1.0f + exp2f(-1.4426950408889634f * x));
}
static __device__ __forceinline__ float tanh_(float x) {
  return 2.0f / (1.0f + exp2f(-2.8853900817779268f * x)) - 1.0f;
}
// raw barrier: LDS ordering only -- does NOT drain vmcnt (the __syncthreads
// vmcnt(0) drain was costing ~1000cy/step of enc-store/prefetch ack wait)
static __device__ __forceinline__ void bar_lds() {
  asm volatile("s_waitcnt lgkmcnt(0)" ::: "memory");
  __builtin_amdgcn_s_barrier();
}

// ---------------------------------------------------------------------------
// Prep: W2 = [w_ih | w_hh] bf16 (2048 x 1024), b_gate = b_ih + b_hh,
// h0 packed bf16x2 -> hx16a, zero padded barrier counters (every launch).
// ---------------------------------------------------------------------------
__global__ __launch_bounds__(256) void prep_kernel(
    const float* __restrict__ w_ih, const float* __restrict__ w_hh,
    const float* __restrict__ b_ih, const float* __restrict__ b_hh,
    const float* __restrict__ h0,
    ushort* __restrict__ W2, float* __restrict__ bgate,
    uint* __restrict__ hx16a, unsigned* __restrict__ bar) {
  int idx = blockIdx.x * 256 + threadIdx.x;
  if (idx < 2048 * 1024) {
    int row = idx >> 10;
    int k = idx & 1023;
    float v = (k < NN) ? w_ih[row * NN + k] : w_hh[row * HH + (k - NN)];
    W2[idx] = f2bf(v);
  }
  if (idx < 2048) bgate[idx] = b_ih[idx] + b_hh[idx];
  if (idx < BB * HH / 2) hx16a[idx] = pk2(h0[2 * idx], h0[2 * idx + 1]);
  if (idx < 16 * 64) bar[idx] = 0u;
}

// ---------------------------------------------------------------------------
// Attention + ax precompute (a = softmax_n(proj_x), timestep-invariant by
// softmax shift invariance). Pass 2 writes bf16 ax into the borrowed
// attentions output region; attn_out itself written by bcast_kernel.
// ---------------------------------------------------------------------------
__global__ __launch_bounds__(256) void attn_kernel(
    const float* __restrict__ x, const float* __restrict__ attn_w,
    float* __restrict__ a_out, ushort* __restrict__ ax) {
  __shared__ float wx[TT];
  __shared__ float as[NN];
  __shared__ float red[8];
  const int b = blockIdx.x;
  const int tid = threadIdx.x;
  wx[tid] = attn_w[2 * HH + tid];
  __syncthreads();

  const float* xb = x + (size_t)b * TT * NN;
  float p0 = 0.0f, p1 = 0.0f;
  for (int t = 0; t < TT; ++t) {
    float w = wx[t];
    p0 += xb[t * NN + tid] * w;
    p1 += xb[t * NN + 256 + tid] * w;
  }

  const int lane = tid & 63, wv = tid >> 6;
  float m = fmaxf(p0, p1);
  #pragma unroll
  for (int o = 32; o; o >>= 1) m = fmaxf(m, __shfl_xor(m, o));
  if (lane == 0) red[wv] = m;
  __syncthreads();
  m = fmaxf(fmaxf(red[0], red[1]), fmaxf(red[2], red[3]));
  float e0 = expf(p0 - m), e1 = expf(p1 - m);
  float s = e0 + e1;
  #pragma unroll
  for (int o = 32; o; o >>= 1) s += __shfl_xor(s, o);
  if (lane == 0) red[4 + wv] = s;
  __syncthreads();
  s = red[4] + red[5] + red[6] + red[7];
  float inv = 1.0f / s;
  float a0 = e0 * inv, a1 = e1 * inv;
  a_out[b * NN + tid] = a0;
  a_out[b * NN + 256 + tid] = a1;
  as[tid] = a0;
  as[tid + 256] = a1;
  __syncthreads();

  const float aa0 = as[tid * 2], aa1 = as[tid * 2 + 1];
  ushort* axb = ax + (size_t)b * TT * NN;
  for (int t = 0; t < TT; ++t) {
    const float2 xv = *(const float2*)(xb + t * NN + tid * 2);
    *(uint*)(axb + t * NN + tid * 2) = pk2(aa0 * xv.x, aa1 * xv.y);
  }
}

// ---------------------------------------------------------------------------
// Final: broadcast a over t into the attentions output.
// ---------------------------------------------------------------------------
__global__ __launch_bounds__(256) void bcast_kernel(
    const float* __restrict__ a, float* __restrict__ attn_out) {
  const size_t idx = (size_t)blockIdx.x * 256 + threadIdx.x;
  const int n4 = (int)(idx & 127);
  const int t = (int)((idx >> 7) & 255);
  const int b = (int)(idx >> 15);
  const float4 v = *(const float4*)(a + b * NN + n4 * 4);
  *(float4*)(attn_out + (((size_t)b * TT + t) * NN + n4 * 4)) = v;
}

// ---------------------------------------------------------------------------
// Persistent LSTM v10 = v9 + critical-path drain removal:
//  * raw LDS-only barriers (lgkmcnt(0)+s_barrier): enc stores (HBM, ~900cy
//    ack) and px prefetch loads no longer drained at B1/B2. vm ordering that
//    MATTERS is kept explicit: h-store ack before arrive (vmcnt 0 there
//    still precedes enc issue); h-load -> ds_write via data dependency.
//  * wave0 issues its h loads right after poll-detect, BEFORE its x-half
//    MFMAs (loads fly under the MFMAs); waves 1..7 keep xmfma->flag->load.
// Everything else identical to v9 (proven).
// ---------------------------------------------------------------------------
__global__ __launch_bounds__(512, 2) void lstm_persistent(
    const ushort* __restrict__ ax,   // (B,T,N) bf16 = a*x
    const ushort* __restrict__ W2,   // (2048,1024) bf16
    const float* __restrict__ bgate, // (2048)
    const float* __restrict__ c0,    // (B,H)
    uint* __restrict__ hx16a, uint* __restrict__ hx16b,  // (B, H/2) bf16x2
    float* __restrict__ enc,         // (B,T,H)
    unsigned* __restrict__ bar) {
  __shared__ ushort hx[16 * 1024];  // 32 KB panel [16 batch][1024 k], swizzled
  __shared__ unsigned warr;         // monotonic wave-arrive counter
  __shared__ unsigned step_flag;    // poll broadcast (monotonic)

  const int tid = threadIdx.x;
  const int lane = tid & 63;
  const int w = tid >> 6;
  const int bg = blockIdx.x & 15;   // XCD-local group
  const int jt = blockIdx.x >> 4;
  const int gb0 = bg * 16;
  unsigned* const barp = bar + bg * 64;  // 256B-padded counter

  if (tid == 0) { warr = 0u; step_flag = 0u; }

  // ---- W2 A-fragments: areg[i] = k-chunk i (uniform across lanes)
  f32x4 areg[32];
  {
    const int r = lane & 15;
    const int grow = (r & 3) * 512 + jt * 32 + w * 4 + (r >> 2);
    const ushort* wp = W2 + (size_t)grow * 1024 + ((lane >> 4) << 3);
    #pragma unroll
    for (int i = 0; i < 32; ++i) {
      areg[i] = *(const f32x4*)(wp + (i << 5));
      asm volatile("" : "+v"(areg[i]));
    }
  }

  // ---- staging geometry: thread = (srow 0..15, sl 0..31)
  const int srow = tid >> 5;
  const int sl = tid & 31;
  const int r7 = srow & 7;

  // ---- per-lane output geometry: (batch eb, col ecol), 4 gates in acc[0..3]
  const int eb = lane & 15;
  const int kq = lane >> 4;
  const int ecol = jt * 32 + w * 4 + kq;
  const float bgi = bgate[ecol];
  const float bgf = bgate[512 + ecol];
  const float bgg = bgate[1024 + ecol];
  const float bgo = bgate[1536 + ecol];
  float c_reg = c0[(size_t)(gb0 + eb) * HH + ecol];

  // ---- MFMA B-read geometry (proven per-iteration XOR addressing)
  const int bbase = (lane & 15) * 1024;
  const int br7 = (lane & 15) & 7;

  // ---- x prefetch for t=0
  uint4 px0, px1;
  {
    const ushort* axp = ax + ((size_t)(gb0 + srow) * TT + 0) * NN;
    px0 = *(const uint4*)(axp + sl * 8);
    px1 = *(const uint4*)(axp + 256 + sl * 8);
  }

  for (int t = 0; t < TT; ++t) {
    const uint* hin = (t & 1) ? hx16b : hx16a;
    uint* hout = (t & 1) ? hx16a : hx16b;

    // ---- stage x-part from prefetch regs; issue prefetch for t+1
    *(uint4*)&hx[srow * 1024 + ((sl ^ r7) << 3)] = px0;
    *(uint4*)&hx[srow * 1024 + (((32 + sl) ^ r7) << 3)] = px1;
    if (t + 1 < TT) {
      const ushort* axp = ax + ((size_t)(gb0 + srow) * TT + (t + 1)) * NN;
      px0 = *(const uint4*)(axp + sl * 8);
      px1 = *(const uint4*)(axp + 256 + sl * 8);
    }
    bar_lds();  // B1: x-panel ready (LDS-only, no vm drain)

    f32x4 acc = {0.f, 0.f, 0.f, 0.f};
    u64 q0, q1, q2, q3;
    const uint* hrow = hin + (size_t)(gb0 + srow) * 256;

    auto xmfma = [&]() {
      #pragma unroll
      for (int ks = 0; ks < 16; ++ks) {
        const int ag = ks * 4 + kq;
        const short8 bf = *(const short8*)&hx[bbase + ((ag ^ br7) << 3)];
        acc = __builtin_amdgcn_mfma_f32_16x16x32_bf16(
            __builtin_bit_cast(short8, areg[ks]), bf, acc, 0, 0, 0);
      }
    };
    auto hload = [&]() {
      q0 = __hip_atomic_load((const u64*)(hrow + sl * 4),
                             __ATOMIC_RELAXED, __HIP_MEMORY_SCOPE_AGENT);
      q1 = __hip_atomic_load((const u64*)(hrow + sl * 4 + 2),
                             __ATOMIC_RELAXED, __HIP_MEMORY_SCOPE_AGENT);
      q2 = __hip_atomic_load((const u64*)(hrow + 128 + sl * 4),
                             __ATOMIC_RELAXED, __HIP_MEMORY_SCOPE_AGENT);
      q3 = __hip_atomic_load((const u64*)(hrow + 128 + sl * 4 + 2),
                             __ATOMIC_RELAXED, __HIP_MEMORY_SCOPE_AGENT);
    };

    if (t == 0) {
      hload();           // h0 pre-staged by prep; no sync needed
      xmfma();
    } else if (w == 0) {
      // poller wave: detect -> broadcast -> issue h loads -> MFMAs cover them
      if (lane == 0) {
        const unsigned target = 16u * (unsigned)t;
        while (__hip_atomic_load(barp, __ATOMIC_RELAXED,
                                 __HIP_MEMORY_SCOPE_AGENT) < target)
          __builtin_amdgcn_s_sleep(1);
        __hip_atomic_store(&step_flag, (unsigned)t, __ATOMIC_RELEASE,
                           __HIP_MEMORY_SCOPE_WORKGROUP);
      }
      asm volatile("" ::: "memory");  // loads stay below the poll
      hload();
      xmfma();
    } else {
      // worker waves: MFMAs overlap the poll; then flag -> loads
      xmfma();
      if (lane == 0) {
        while (__hip_atomic_load(&step_flag, __ATOMIC_ACQUIRE,
                                 __HIP_MEMORY_SCOPE_WORKGROUP) < (unsigned)t) {}
      }
      asm volatile("" ::: "memory");  // loads stay below the flag gate
      hload();
    }

    // ---- stage h-part (ds_write waits on loads via data dependency)
    {
      uint4 p0, p1;
      p0.x = (uint)q0; p0.y = (uint)(q0 >> 32);
      p0.z = (uint)q1; p0.w = (uint)(q1 >> 32);
      p1.x = (uint)q2; p1.y = (uint)(q2 >> 32);
      p1.z = (uint)q3; p1.w = (uint)(q3 >> 32);
      *(uint4*)&hx[srow * 1024 + (((64 + sl) ^ r7) << 3)] = p0;
      *(uint4*)&hx[srow * 1024 + (((96 + sl) ^ r7) << 3)] = p1;
    }
    bar_lds();  // B2: h-panel ready (LDS-only, no vm drain)

    // ---- h-half MFMAs
    #pragma unroll
    for (int ks = 16; ks < 32; ++ks) {
      const int ag = ks * 4 + kq;
      const short8 bf = *(const short8*)&hx[bbase + ((ag ^ br7) << 3)];
      acc = __builtin_amdgcn_mfma_f32_16x16x32_bf16(
          __builtin_bit_cast(short8, areg[ks]), bf, acc, 0, 0, 0);
    }

    // ---- in-lane LSTM cell; publish h; combined arrive
    {
      const float ig = sigm_(acc[0] + bgi);
      const float fg = sigm_(acc[1] + bgf);
      const float gg = tanh_(acc[2] + bgg);
      const float og = sigm_(acc[3] + bgo);
      const float cn = fg * c_reg + ig * gg;
      const float hn = og * tanh_(cn);
      c_reg = cn;
      const float hp_ = __shfl_xor(hn, 16);   // partner col (kq^1)
      if (!(lane & 16)) {                     // kq even lanes store the pair
        __hip_atomic_store(hout + (size_t)(gb0 + eb) * 256 + (ecol >> 1),
                           pk2(hn, hp_),
                           __ATOMIC_RELAXED, __HIP_MEMORY_SCOPE_AGENT);
      }
      asm volatile("s_waitcnt vmcnt(0)" ::: "memory");  // wave's h at MALL
      if (lane == 0) {
        const unsigned old = __hip_atomic_fetch_add(
            &warr, 1u, __ATOMIC_ACQ_REL, __HIP_MEMORY_SCOPE_WORKGROUP);
        if (old == 8u * (unsigned)t + 7u)     // last of 8 waves: one global add
          __hip_atomic_fetch_add(barp, 1u, __ATOMIC_RELAXED,
                                 __HIP_MEMORY_SCOPE_AGENT);
      }
      enc[((size_t)(gb0 + eb) * TT + t) * HH + ecol] = hn;  // never drained
    }
  }
}

extern "C" void kernel_launch(void* const* d_in, const int* in_sizes, int n_in,
                              void* d_out, int out_size, void* d_ws, size_t ws_size,
                              hipStream_t stream) {
  const float* x      = (const float*)d_in[0];
  const float* h0     = (const float*)d_in[1];
  const float* c0     = (const float*)d_in[2];
  const float* attn_w = (const float*)d_in[3];
  // d_in[4] = attn_b: softmax-shift-invariant -> unused
  const float* w_ih   = (const float*)d_in[5];
  const float* w_hh   = (const float*)d_in[6];
  const float* b_ih   = (const float*)d_in[7];
  const float* b_hh   = (const float*)d_in[8];

  float* attn_out = (float*)d_out;                         // (B,T,N)
  float* enc_out  = (float*)d_out + (size_t)BB * TT * NN;  // (B,T,H)
  // borrow the attn output region for bf16 ax (64 MB of 128 MB) until bcast
  ushort* ax = (ushort*)d_out;

  char* ws = (char*)d_ws;
  float*    a_ws  = (float*)(ws);                    // 512 KB
  ushort*   W2_ws = (ushort*)(ws + 0x80000);         // 4 MB
  float*    bg_ws = (float*)(ws + 0x480000);         // 8 KB
  uint*     hx16a = (uint*)(ws + 0x482000);          // 256 KB
  uint*     hx16b = (uint*)(ws + 0x4C2000);          // 256 KB
  unsigned* bar   = (unsigned*)(ws + 0x502000);      // 4 KB (16 x 256B)

  prep_kernel<<<8192, 256, 0, stream>>>(w_ih, w_hh, b_ih, b_hh, h0,
                                        W2_ws, bg_ws, hx16a, bar);
  attn_kernel<<<BB, 256, 0, stream>>>(x, attn_w, a_ws, ax);

  {
    dim3 grid(256), block(512);
    void* args[] = {(void*)&ax, (void*)&W2_ws, (void*)&bg_ws, (void*)&c0,
                    (void*)&hx16a, (void*)&hx16b, (void*)&enc_out,
                    (void*)&bar};
    hipLaunchCooperativeKernel((void*)lstm_persistent, grid, block, args, 0,
                               stream);
  }

  bcast_kernel<<<32768, 256, 0, stream>>>(a_ws, attn_out);
}